// Round 6
// baseline (413.128 us; speedup 1.0000x reference)
//
#include <hip/hip_runtime.h>
#include <hip/hip_cooperative_groups.h>
#include <math.h>

namespace cg = cooperative_groups;

#define GH 224
#define GW 224
#define GN (GH*GW)          // 50176
#define NT 25
#define NG 20               // distinct d2 values in 11x11 window
#define CAP 24576           // per-image (birth,death) list capacity
#define TILES_X 8           // 28 px wide each (8*28 = 224 exact)
#define TILES_Y 38          // 6 px tall each (38*6 = 228, tail masked)
#define TPI (TILES_X*TILES_Y)   // 304 tiles per image
#define NTILES (12*TPI)         // 3648
#define NSUMJ 588               // 12 images * 49 chunks of 1024 px
#define WTW 40              // w-tile: (28+2)+10 wide
#define WTH 18              // (6+2)+10 tall
#define WTN (WTW*WTH)       // 720
#define NB_COOP 784

// ws float offsets:
// [0..16)    unused (zeroed)
// [16..40)   per-idx (mn_invbits, mx_bits) via uint atomicMax
// [48..60)   per-idx minima-list counters (int)
// [60]       ticket (int)
// [64..664)  lam[12][50]
// [700..1288) 588 per-chunk sum partials
// [2048..)   per-image lists: float2[CAP] each
#define WS_MM   16
#define WS_CTR  48
#define WS_TICK 60
#define WS_LAM  64
#define WS_SUMP 700
#define WS_LIST 2048

// compile-time stable-sorted neighbor table (matches np.argsort(d2, kind="stable"))
// plus distance-group partition: within an equal-d2 run the sequential clip-fill
// equals one clip of the group sum (121 serial steps -> 20). Verified R4 (absmax 0).
struct NbrTbl { int off[121]; int gid[121]; float gd2[NG]; };
constexpr NbrTbl make_tbl() {
    NbrTbl t{};
    float ds[121] = {};
    for (int i = 0; i < 121; i++) {
        int dy = i / 11 - 5, dx = i % 11 - 5;
        int d2 = dy*dy + dx*dx;
        int rank = 0;
        for (int j = 0; j < 121; j++) {
            int ey = j / 11 - 5, ex = j % 11 - 5;
            int e2 = ey*ey + ex*ex;
            rank += (e2 < d2) || (e2 == d2 && j < i);
        }
        t.off[rank] = (dy + 5) * WTW + (dx + 5);
        ds[rank]    = (float)d2;
    }
    int g = 0;
    t.gid[0] = 0; t.gd2[0] = ds[0];
    for (int r = 1; r < 121; r++) {
        if (ds[r] != ds[r-1]) { g++; t.gd2[g] = ds[r]; }
        t.gid[r] = g;
    }
    return t;
}
constexpr NbrTbl TBL = make_tbl();

// ---- shared phase implementations ----

__device__ __forceinline__ void sums_job(int j, const float* __restrict__ in,
                                         float* __restrict__ ws) {
    __shared__ float sh4[4];
    __syncthreads();
    int idx = j / 49, chunk = j % 49;
    int cc = idx >> 2, bb = idx & 3;
    const float4* w4 = (const float4*)(in + (size_t)(bb*3 + cc) * GN);
    float4 v = w4[chunk*256 + threadIdx.x];
    float s = v.x + v.y + v.z + v.w;
    #pragma unroll
    for (int off = 32; off; off >>= 1) s += __shfl_down(s, off);
    if ((threadIdx.x & 63) == 0) sh4[threadIdx.x >> 6] = s;
    __syncthreads();
    if (threadIdx.x == 0) ws[WS_SUMP + j] = sh4[0] + sh4[1] + sh4[2] + sh4[3];
}

__device__ __forceinline__ void dtm_tile(int tile_id, const float* __restrict__ in,
                                         float* __restrict__ ws) {
    __shared__ float wt[WTN];
    __shared__ float Ft[256];          // 8 rows x stride 32 (cols 0..29 valid)
    __shared__ float sb[192], sd[192];
    __shared__ float smn[4], smx[4];
    __shared__ float sbound;
    __shared__ int lcnt, gbase;
    const int tid = threadIdx.x;
    __syncthreads();                   // LDS reuse guard across strided iterations

    int idx  = tile_id / TPI;
    int trem = tile_id % TPI;
    int tyi = trem / TILES_X, txi = trem % TILES_X;
    int gy = tyi*6, gx = txi*28;       // interior origin
    int cc = idx >> 2, bb = idx & 3;
    const float* w = in + (size_t)(bb*3 + cc) * GN;

    // bound = 0.05 * sum(image) from 49 partials (fixed-order -> bitwise same per image)
    if (tid < 64) {
        float p = (tid < 49) ? ws[WS_SUMP + idx*49 + tid] : 0.f;
        #pragma unroll
        for (int off = 32; off; off >>= 1) p += __shfl_down(p, off);
        if (tid == 0) { sbound = 0.05f * p; lcnt = 0; }
    }

    // stage border-clamped w halo tile 18x40
    int wy0 = gy - 6, wx0 = gx - 6;
    for (int i = tid; i < WTN; i += 256) {
        int r = i / WTW, q = i % WTW;
        int yy = wy0 + r; yy = yy < 0 ? 0 : (yy > GH-1 ? GH-1 : yy);
        int xx = wx0 + q; xx = xx < 0 ? 0 : (xx > GW-1 ? GW-1 : xx);
        wt[i] = w[yy*GW + xx];
    }
    __syncthreads();

    float bound = sbound;
    int fx = tid & 31, fy = tid >> 5;
    float f = 0.f;
    float mnv = INFINITY, mxv = -INFINITY;
    if (fx < 30) {
        // F point = interior-1 + (fy,fx); halo points computed at CLAMPED center
        int py0 = gy - 1 + fy; int pyc = py0 < 0 ? 0 : (py0 > GH-1 ? GH-1 : py0);
        int px0 = gx - 1 + fx; int pxc = px0 < 0 ? 0 : (px0 > GW-1 ? GW-1 : px0);
        const float* basep = wt + (pyc - wy0 - 5)*WTW + (pxc - wx0 - 5);
        float grp[NG];
        #pragma unroll
        for (int g = 0; g < NG; g++) grp[g] = 0.f;
        #pragma unroll
        for (int j = 0; j < 121; j++) grp[TBL.gid[j]] += basep[TBL.off[j]];
        float cum = 0.f, acc = 0.f;
        #pragma unroll
        for (int g = 0; g < NG; g++) {
            float v = bound - cum;
            v = v < 0.f ? 0.f : v;
            v = v > grp[g] ? grp[g] : v;
            acc = fmaf(v, TBL.gd2[g], acc);
            cum += grp[g];
        }
        f = sqrtf(acc / bound + 1e-12f);
        Ft[fy*32 + fx] = f;
        mnv = f; mxv = f;              // halo/invalid are clamped duplicates -> safe
    }
    #pragma unroll
    for (int off = 32; off; off >>= 1) {
        mnv = fminf(mnv, __shfl_down(mnv, off));
        mxv = fmaxf(mxv, __shfl_down(mxv, off));
    }
    if ((tid & 63) == 0) { smn[tid>>6] = mnv; smx[tid>>6] = mxv; }
    __syncthreads();                   // Ft complete + smn/smx ready
    if (tid == 0) {
        float bm = fminf(fminf(smn[0], smn[1]), fminf(smn[2], smn[3]));
        float bX = fmaxf(fmaxf(smx[0], smx[1]), fmaxf(smx[2], smx[3]));
        atomicMax((unsigned int*)&ws[WS_MM + 2*idx], ~__float_as_uint(bm));
        atomicMax((unsigned int*)&ws[WS_MM + 2*idx + 1], __float_as_uint(bX));
    }

    // 3x3 is_min / death on 28x6 interior (x exact, y tail masked)
    if (fy >= 1 && fy <= 6 && fx >= 1 && fx <= 28) {
        int py = gy + fy - 1;
        if (py < GH) {
            const float* Fc = Ft + (fy-1)*32 + (fx-1);
            float mn = f, mx = f;
            #pragma unroll
            for (int dy = 0; dy < 3; dy++)
                #pragma unroll
                for (int dx = 0; dx < 3; dx++) {
                    float v = Fc[dy*32 + dx];
                    mn = fminf(mn, v); mx = fmaxf(mx, v);
                }
            if (f <= mn) {
                int s = atomicAdd(&lcnt, 1);
                sb[s] = f; sd[s] = mx;
            }
        }
    }
    __syncthreads();
    if (tid == 0) gbase = atomicAdd((int*)ws + WS_CTR + idx, lcnt);
    __syncthreads();
    int n = lcnt, gb = gbase;
    float2* list = (float2*)(ws + WS_LIST) + (size_t)idx * CAP;
    for (int i = tid; i < n; i += 256)
        if (gb + i < CAP) list[gb + i] = make_float2(sb[i], sd[i]);
}

__device__ __forceinline__ void top2_job(int jb, float* __restrict__ ws) {
    __shared__ float r0s[4], r1s[4];
    __syncthreads();
    int idx = jb / NT, t = jb % NT;
    int nm = ((volatile int*)ws)[WS_CTR + idx]; if (nm > CAP) nm = CAP;
    float tmin = __uint_as_float(~((const unsigned int*)ws)[WS_MM + 2*idx]);
    float tmax = __uint_as_float( ((const unsigned int*)ws)[WS_MM + 2*idx + 1]);
    float tss = tmin + (tmax - tmin) * ((float)t / 24.0f);
    const float2* list = (const float2*)(ws + WS_LIST) + (size_t)idx * CAP;
    float a0 = 0.f, a1 = 0.f;
    for (int i = threadIdx.x; i < nm; i += 256) {
        float2 p = list[i];
        float v = fmaxf(fminf(tss - p.x, p.y - tss), 0.f);
        float n0 = fmaxf(a0, v);
        a1 = fmaxf(a1, fminf(a0, v));
        a0 = n0;
    }
    #pragma unroll
    for (int off = 32; off; off >>= 1) {
        float b0 = __shfl_down(a0, off);
        float b1 = __shfl_down(a1, off);
        float n0 = fmaxf(a0, b0);
        a1 = fmaxf(fminf(a0, b0), fmaxf(a1, b1));
        a0 = n0;
    }
    if ((threadIdx.x & 63) == 0) { r0s[threadIdx.x>>6] = a0; r1s[threadIdx.x>>6] = a1; }
    __syncthreads();
    if (threadIdx.x == 0) {
        float c0 = r0s[0], c1 = r1s[0];
        #pragma unroll
        for (int wv = 1; wv < 4; wv++) {
            float b0 = r0s[wv], b1 = r1s[wv];
            float n0 = fmaxf(c0, b0);
            c1 = fmaxf(fminf(c0, b0), fmaxf(c1, b1));
            c0 = n0;
        }
        ws[WS_LAM + (size_t)idx * 50 + t*2    ] = c0;
        ws[WS_LAM + (size_t)idx * 50 + t*2 + 1] = c1;
    }
}

__device__ __forceinline__ void head_job(const float* __restrict__ W1, const float* __restrict__ b1,
                                         const float* __restrict__ W2, const float* __restrict__ b2,
                                         const float* __restrict__ W3, const float* __restrict__ b3,
                                         const float* __restrict__ fcw, const float* __restrict__ fcb,
                                         const float* __restrict__ ws, float* __restrict__ out) {
    __shared__ float lamS[600];
    __shared__ float xsh[600];
    int tid = threadIdx.x;
    volatile const float* vl = ws + WS_LAM;     // L1-bypass: lam written by other blocks
    for (int i = tid; i < 600; i += 256) lamS[i] = vl[i];
    __syncthreads();
    for (int j = tid; j < 600; j += 256) {
        int b = j / 150, r = j % 150, c = r / 50, o = r % 50;
        const float* Wc = (c == 0) ? W1 : (c == 1) ? W2 : W3;
        const float* bc = (c == 0) ? b1 : (c == 1) ? b2 : b3;
        const float* lam = lamS + (c*4 + b) * 50;
        float acc = bc[o];
        for (int f2 = 0; f2 < 50; f2++) acc += lam[f2] * Wc[o*50 + f2];
        xsh[j] = acc;
    }
    __syncthreads();
    if (tid < 150) {
        float s = 0.f;
        for (int b = 0; b < 4; b++) s += fabsf(xsh[b*150 + tid]);
        out[28 + tid] = s;
    }
    if (tid < 28) {
        int b = tid / 7, o = tid % 7;
        float acc = fcb[o];
        for (int j = 0; j < 150; j++) acc += fmaxf(xsh[b*150 + j], 0.f) * fcw[o*150 + j];
        out[b*7 + o] = acc;
    }
}

// ---- cooperative single-kernel path ----
__global__ __launch_bounds__(256) void k_all(
        const float* __restrict__ in,
        const float* __restrict__ W1, const float* __restrict__ b1,
        const float* __restrict__ W2, const float* __restrict__ b2,
        const float* __restrict__ W3, const float* __restrict__ b3,
        const float* __restrict__ fcw, const float* __restrict__ fcb,
        float* __restrict__ ws, float* __restrict__ out)
{
    cg::grid_group grid = cg::this_grid();
    const int nb = gridDim.x;
    if (blockIdx.x == 0 && threadIdx.x < 64) ws[threadIdx.x] = 0.f;
    for (int j = blockIdx.x; j < NSUMJ; j += nb) sums_job(j, in, ws);
    grid.sync();
    for (int t = blockIdx.x; t < NTILES; t += nb) dtm_tile(t, in, ws);
    grid.sync();
    for (int j = blockIdx.x; j < 300; j += nb) top2_job(j, ws);
    grid.sync();
    if (blockIdx.x == 0) head_job(W1, b1, W2, b2, W3, b3, fcw, fcb, ws, out);
}

// ---- fallback multi-kernel path (3 nodes) ----
__global__ __launch_bounds__(256) void k_sums(const float* __restrict__ in, float* __restrict__ ws) {
    if (blockIdx.x == 0 && threadIdx.x < 64) ws[threadIdx.x] = 0.f;  // ctl zeroing
    sums_job(blockIdx.x, in, ws);
}

__global__ __launch_bounds__(256) void k_dtm(const float* __restrict__ in, float* __restrict__ ws) {
    dtm_tile(blockIdx.x, in, ws);
}

__global__ __launch_bounds__(256) void k_top2head(
        const float* __restrict__ W1, const float* __restrict__ b1,
        const float* __restrict__ W2, const float* __restrict__ b2,
        const float* __restrict__ W3, const float* __restrict__ b3,
        const float* __restrict__ fcw, const float* __restrict__ fcb,
        float* __restrict__ ws, float* __restrict__ out)
{
    top2_job(blockIdx.x, ws);
    __threadfence();                              // release lam store
    __shared__ int tick;
    __syncthreads();
    if (threadIdx.x == 0) tick = atomicAdd((int*)ws + WS_TICK, 1);
    __syncthreads();
    if (tick == 299) {                            // last block: all lam visible
        __threadfence();                          // acquire
        head_job(W1, b1, W2, b2, W3, b3, fcw, fcb, ws, out);
    }
}

extern "C" void kernel_launch(void* const* d_in, const int* in_sizes, int n_in,
                              void* d_out, int out_size, void* d_ws, size_t ws_size,
                              hipStream_t stream) {
    const float* in  = (const float*)d_in[0];
    const float* W1  = (const float*)d_in[1];
    const float* b1  = (const float*)d_in[2];
    const float* W2  = (const float*)d_in[3];
    const float* b2  = (const float*)d_in[4];
    const float* W3  = (const float*)d_in[5];
    const float* b3  = (const float*)d_in[6];
    const float* fcw = (const float*)d_in[7];
    const float* fcb = (const float*)d_in[8];
    float* ws  = (float*)d_ws;
    float* out = (float*)d_out;

    void* args[] = { (void*)&in, (void*)&W1, (void*)&b1, (void*)&W2, (void*)&b2,
                     (void*)&W3, (void*)&b3, (void*)&fcw, (void*)&fcb,
                     (void*)&ws, (void*)&out };
    hipError_t err = hipLaunchCooperativeKernel((const void*)k_all, dim3(NB_COOP),
                                                dim3(256), args, 0, stream);
    if (err != hipSuccess) {
        (void)hipGetLastError();                  // clear sticky error
        k_sums    <<<NSUMJ,  256, 0, stream>>>(in, ws);
        k_dtm     <<<NTILES, 256, 0, stream>>>(in, ws);
        k_top2head<<<300,    256, 0, stream>>>(W1, b1, W2, b2, W3, b3, fcw, fcb, ws, out);
    }
}

// Round 7
// 184.718 us; speedup vs baseline: 2.2365x; 2.2365x over previous
//
#include <hip/hip_runtime.h>
#include <math.h>

#define GH 224
#define GW 224
#define GN (GH*GW)          // 50176
#define NT 25
#define NG 20               // distinct d2 values in 11x11 window
#define CAP 24576           // per-image (birth,death) list capacity
#define TILES_X 8           // 28 px wide each (8*28 = 224 exact)
#define TILES_Y 38          // 6 px tall each (38*6 = 228, tail masked)
#define TPI (TILES_X*TILES_Y)   // 304 tiles per image
#define NTILES (12*TPI)         // 3648
#define NSUMJ 588               // 12 images * 49 chunks of 1024 px
#define WTW 40              // w-tile: (28+2)+10 wide
#define WTH 18              // (6+2)+10 tall
#define WTN (WTW*WTH)       // 720

// ws float offsets:
// [16..40)   per-idx (mn_invbits, mx_bits) via uint atomicMax
// [48..60)   per-idx minima-list counters (int)
// [60]       ticket (int)
// [64..664)  lam[12][50]
// [700..1288) 588 per-chunk sum partials
// [2048..)   per-image lists: float2[CAP] each
#define WS_MM   16
#define WS_CTR  48
#define WS_TICK 60
#define WS_LAM  64
#define WS_SUMP 700
#define WS_LIST 2048

// compile-time stable-sorted neighbor table (matches np.argsort(d2, kind="stable"))
// plus distance-group partition: within an equal-d2 run the sequential clip-fill
// equals one clip of the group sum (121 serial steps -> 20). HW-verified R4/R6 (absmax 0).
struct NbrTbl { int off[121]; int gid[121]; float gd2[NG]; };
constexpr NbrTbl make_tbl() {
    NbrTbl t{};
    float ds[121] = {};
    for (int i = 0; i < 121; i++) {
        int dy = i / 11 - 5, dx = i % 11 - 5;
        int d2 = dy*dy + dx*dx;
        int rank = 0;
        for (int j = 0; j < 121; j++) {
            int ey = j / 11 - 5, ex = j % 11 - 5;
            int e2 = ey*ey + ex*ex;
            rank += (e2 < d2) || (e2 == d2 && j < i);
        }
        t.off[rank] = (dy + 5) * WTW + (dx + 5);
        ds[rank]    = (float)d2;
    }
    int g = 0;
    t.gid[0] = 0; t.gd2[0] = ds[0];
    for (int r = 1; r < 121; r++) {
        if (ds[r] != ds[r-1]) { g++; t.gd2[g] = ds[r]; }
        t.gid[r] = g;
    }
    return t;
}
constexpr NbrTbl TBL = make_tbl();

// Node 1: control-slot zeroing + per-image chunk sum partials (fixed order).
__global__ __launch_bounds__(256) void k_sums(const float* __restrict__ in, float* __restrict__ ws) {
    __shared__ float sh4[4];
    if (blockIdx.x == 0 && threadIdx.x < 64) ws[threadIdx.x] = 0.f;
    int j = blockIdx.x;
    int idx = j / 49, chunk = j % 49;
    int cc = idx >> 2, bb = idx & 3;
    const float4* w4 = (const float4*)(in + (size_t)(bb*3 + cc) * GN);
    float4 v = w4[chunk*256 + threadIdx.x];
    float s = v.x + v.y + v.z + v.w;
    #pragma unroll
    for (int off = 32; off; off >>= 1) s += __shfl_down(s, off);
    if ((threadIdx.x & 63) == 0) sh4[threadIdx.x >> 6] = s;
    __syncthreads();
    if (threadIdx.x == 0) ws[WS_SUMP + j] = sh4[0] + sh4[1] + sh4[2] + sh4[3];
}

// Node 2: DTM + 3x3 min/max + global minmax + minima compaction per 28x6 tile.
__global__ __launch_bounds__(256) void k_dtm(const float* __restrict__ in, float* __restrict__ ws) {
    __shared__ float wt[WTN];
    __shared__ float Ft[256];          // 8 rows x stride 32 (cols 0..29 valid)
    __shared__ float sb[192], sd[192];
    __shared__ float smn[4], smx[4];
    __shared__ float sbound;
    __shared__ int lcnt, gbase;
    const int tid = threadIdx.x;

    int tile_id = blockIdx.x;
    int idx  = tile_id / TPI;
    int trem = tile_id % TPI;
    int tyi = trem / TILES_X, txi = trem % TILES_X;
    int gy = tyi*6, gx = txi*28;       // interior origin
    int cc = idx >> 2, bb = idx & 3;
    const float* w = in + (size_t)(bb*3 + cc) * GN;

    // bound = 0.05 * sum(image) from 49 partials (fixed-order -> identical per image)
    if (tid < 64) {
        float p = (tid < 49) ? ws[WS_SUMP + idx*49 + tid] : 0.f;
        #pragma unroll
        for (int off = 32; off; off >>= 1) p += __shfl_down(p, off);
        if (tid == 0) { sbound = 0.05f * p; lcnt = 0; }
    }

    // stage border-clamped w halo tile 18x40
    int wy0 = gy - 6, wx0 = gx - 6;
    for (int i = tid; i < WTN; i += 256) {
        int r = i / WTW, q = i % WTW;
        int yy = wy0 + r; yy = yy < 0 ? 0 : (yy > GH-1 ? GH-1 : yy);
        int xx = wx0 + q; xx = xx < 0 ? 0 : (xx > GW-1 ? GW-1 : xx);
        wt[i] = w[yy*GW + xx];
    }
    __syncthreads();

    float bound = sbound;
    int fx = tid & 31, fy = tid >> 5;
    float f = 0.f;
    float mnv = INFINITY, mxv = -INFINITY;
    if (fx < 30) {
        // F point = interior-1 + (fy,fx); halo points computed at CLAMPED center
        int py0 = gy - 1 + fy; int pyc = py0 < 0 ? 0 : (py0 > GH-1 ? GH-1 : py0);
        int px0 = gx - 1 + fx; int pxc = px0 < 0 ? 0 : (px0 > GW-1 ? GW-1 : px0);
        const float* basep = wt + (pyc - wy0 - 5)*WTW + (pxc - wx0 - 5);
        float grp[NG];
        #pragma unroll
        for (int g = 0; g < NG; g++) grp[g] = 0.f;
        #pragma unroll
        for (int j = 0; j < 121; j++) grp[TBL.gid[j]] += basep[TBL.off[j]];
        float cum = 0.f, acc = 0.f;
        #pragma unroll
        for (int g = 0; g < NG; g++) {
            float v = bound - cum;
            v = v < 0.f ? 0.f : v;
            v = v > grp[g] ? grp[g] : v;
            acc = fmaf(v, TBL.gd2[g], acc);
            cum += grp[g];
        }
        f = sqrtf(acc / bound + 1e-12f);
        Ft[fy*32 + fx] = f;
        mnv = f; mxv = f;              // halo/invalid are clamped duplicates -> safe
    }
    #pragma unroll
    for (int off = 32; off; off >>= 1) {
        mnv = fminf(mnv, __shfl_down(mnv, off));
        mxv = fmaxf(mxv, __shfl_down(mxv, off));
    }
    if ((tid & 63) == 0) { smn[tid>>6] = mnv; smx[tid>>6] = mxv; }
    __syncthreads();                   // Ft complete + smn/smx ready
    if (tid == 0) {
        float bm = fminf(fminf(smn[0], smn[1]), fminf(smn[2], smn[3]));
        float bX = fmaxf(fmaxf(smx[0], smx[1]), fmaxf(smx[2], smx[3]));
        atomicMax((unsigned int*)&ws[WS_MM + 2*idx], ~__float_as_uint(bm));
        atomicMax((unsigned int*)&ws[WS_MM + 2*idx + 1], __float_as_uint(bX));
    }

    // 3x3 is_min / death on 28x6 interior (x exact, y tail masked)
    if (fy >= 1 && fy <= 6 && fx >= 1 && fx <= 28) {
        int py = gy + fy - 1;
        if (py < GH) {
            const float* Fc = Ft + (fy-1)*32 + (fx-1);
            float mn = f, mx = f;
            #pragma unroll
            for (int dy = 0; dy < 3; dy++)
                #pragma unroll
                for (int dx = 0; dx < 3; dx++) {
                    float v = Fc[dy*32 + dx];
                    mn = fminf(mn, v); mx = fmaxf(mx, v);
                }
            if (f <= mn) {
                int s = atomicAdd(&lcnt, 1);
                sb[s] = f; sd[s] = mx;
            }
        }
    }
    __syncthreads();
    if (tid == 0) gbase = atomicAdd((int*)ws + WS_CTR + idx, lcnt);
    __syncthreads();
    int n = lcnt, gb = gbase;
    float2* list = (float2*)(ws + WS_LIST) + (size_t)idx * CAP;
    for (int i = tid; i < n; i += 256)
        if (gb + i < CAP) list[gb + i] = make_float2(sb[i], sd[i]);
}

// Node 3: top-2 landscape per (image,t) + ticket -> last block runs the heads.
__global__ __launch_bounds__(256) void k_top2head(
        const float* __restrict__ W1, const float* __restrict__ b1,
        const float* __restrict__ W2, const float* __restrict__ b2,
        const float* __restrict__ W3, const float* __restrict__ b3,
        const float* __restrict__ fcw, const float* __restrict__ fcb,
        float* __restrict__ ws, float* __restrict__ out)
{
    __shared__ float r0s[4], r1s[4];
    __shared__ int tick;
    const int tid = threadIdx.x;
    {
        int jb = blockIdx.x;
        int idx = jb / NT, t = jb % NT;
        int nm = ((const int*)ws)[WS_CTR + idx]; if (nm > CAP) nm = CAP;
        float tmin = __uint_as_float(~((const unsigned int*)ws)[WS_MM + 2*idx]);
        float tmax = __uint_as_float( ((const unsigned int*)ws)[WS_MM + 2*idx + 1]);
        float tss = tmin + (tmax - tmin) * ((float)t / 24.0f);
        const float2* list = (const float2*)(ws + WS_LIST) + (size_t)idx * CAP;
        float a0 = 0.f, a1 = 0.f;
        for (int i = tid; i < nm; i += 256) {
            float2 p = list[i];
            float v = fmaxf(fminf(tss - p.x, p.y - tss), 0.f);
            float n0 = fmaxf(a0, v);
            a1 = fmaxf(a1, fminf(a0, v));
            a0 = n0;
        }
        #pragma unroll
        for (int off = 32; off; off >>= 1) {
            float b0 = __shfl_down(a0, off);
            float b1 = __shfl_down(a1, off);
            float n0 = fmaxf(a0, b0);
            a1 = fmaxf(fminf(a0, b0), fmaxf(a1, b1));
            a0 = n0;
        }
        if ((tid & 63) == 0) { r0s[tid>>6] = a0; r1s[tid>>6] = a1; }
        __syncthreads();
        if (tid == 0) {
            float c0 = r0s[0], c1 = r1s[0];
            #pragma unroll
            for (int wv = 1; wv < 4; wv++) {
                float b0 = r0s[wv], b1 = r1s[wv];
                float n0 = fmaxf(c0, b0);
                c1 = fmaxf(fminf(c0, b0), fmaxf(c1, b1));
                c0 = n0;
            }
            // agent-scope stores: lam must be coherent across XCDs for the head block
            __hip_atomic_store(&ws[WS_LAM + (size_t)idx*50 + t*2],     c0,
                               __ATOMIC_RELAXED, __HIP_MEMORY_SCOPE_AGENT);
            __hip_atomic_store(&ws[WS_LAM + (size_t)idx*50 + t*2 + 1], c1,
                               __ATOMIC_RELAXED, __HIP_MEMORY_SCOPE_AGENT);
        }
    }
    __threadfence();                              // release
    __syncthreads();
    if (tid == 0) tick = atomicAdd((int*)ws + WS_TICK, 1);
    __syncthreads();
    if (tick != 299) return;                      // last-arriving block runs the heads
    __threadfence();                              // acquire

    __shared__ float lamS[600];
    __shared__ float xsh[600];
    for (int i = tid; i < 600; i += 256)
        lamS[i] = __hip_atomic_load(&ws[WS_LAM + i], __ATOMIC_RELAXED,
                                    __HIP_MEMORY_SCOPE_AGENT);
    __syncthreads();
    for (int j = tid; j < 600; j += 256) {
        int b = j / 150, r = j % 150, c = r / 50, o = r % 50;
        const float* Wc = (c == 0) ? W1 : (c == 1) ? W2 : W3;
        const float* bc = (c == 0) ? b1 : (c == 1) ? b2 : b3;
        const float* lam = lamS + (c*4 + b) * 50;
        float acc = bc[o];
        for (int f2 = 0; f2 < 50; f2++) acc += lam[f2] * Wc[o*50 + f2];
        xsh[j] = acc;
    }
    __syncthreads();
    if (tid < 150) {                     // signal = sum_b |x|
        float s = 0.f;
        for (int b = 0; b < 4; b++) s += fabsf(xsh[b*150 + tid]);
        out[28 + tid] = s;
    }
    if (tid < 28) {                      // output = relu(x) @ fc_w.T + fc_b
        int b = tid / 7, o = tid % 7;
        float acc = fcb[o];
        for (int j = 0; j < 150; j++) acc += fmaxf(xsh[b*150 + j], 0.f) * fcw[o*150 + j];
        out[b*7 + o] = acc;
    }
}

extern "C" void kernel_launch(void* const* d_in, const int* in_sizes, int n_in,
                              void* d_out, int out_size, void* d_ws, size_t ws_size,
                              hipStream_t stream) {
    const float* in  = (const float*)d_in[0];
    const float* W1  = (const float*)d_in[1];
    const float* b1  = (const float*)d_in[2];
    const float* W2  = (const float*)d_in[3];
    const float* b2  = (const float*)d_in[4];
    const float* W3  = (const float*)d_in[5];
    const float* b3  = (const float*)d_in[6];
    const float* fcw = (const float*)d_in[7];
    const float* fcb = (const float*)d_in[8];
    float* ws  = (float*)d_ws;
    float* out = (float*)d_out;

    k_sums    <<<NSUMJ,  256, 0, stream>>>(in, ws);
    k_dtm     <<<NTILES, 256, 0, stream>>>(in, ws);
    k_top2head<<<300,    256, 0, stream>>>(W1, b1, W2, b2, W3, b3, fcw, fcb, ws, out);
}

// Round 8
// 146.545 us; speedup vs baseline: 2.8191x; 1.2605x over previous
//
#include <hip/hip_runtime.h>
#include <math.h>

#define GH 224
#define GW 224
#define GN (GH*GW)          // 50176
#define NT 25
#define NG 20               // distinct d2 values in 11x11 window
#define CAP 24576           // per-image (birth,death) list capacity
#define TILES_X 8           // 28 px wide  (8*28 = 224 exact)
#define TILES_Y 16          // 14 px tall  (16*14 = 224 exact)
#define TPI (TILES_X*TILES_Y)   // 128 tiles per image
#define NTILES (12*TPI)         // 1536
#define NSUMJ 588               // 12 images * 49 chunks of 1024 px
#define WTW 40              // w-tile: (28+2)+10 wide
#define WTH 26              // (14+2)+10 tall
#define WTN (WTW*WTH)       // 1040

// ws float offsets:
// [16..40)   per-idx (mn_invbits, mx_bits) via uint atomicMax
// [48..60)   per-idx minima-list counters (int)
// [60]       ticket (int)
// [64..664)  lam[12][50]
// [700..1288) 588 per-chunk sum partials
// [2048..)   per-image lists: float2[CAP] each
#define WS_MM   16
#define WS_CTR  48
#define WS_TICK 60
#define WS_LAM  64
#define WS_SUMP 700
#define WS_LIST 2048

// compile-time stable-sorted neighbor table (matches np.argsort(d2, kind="stable"))
// plus distance-group partition: within an equal-d2 run the sequential clip-fill
// equals one clip of the group sum (121 serial steps -> 20). HW-verified R4/R6/R7.
struct NbrTbl { int off[121]; int gid[121]; float gd2[NG]; };
constexpr NbrTbl make_tbl() {
    NbrTbl t{};
    float ds[121] = {};
    for (int i = 0; i < 121; i++) {
        int dy = i / 11 - 5, dx = i % 11 - 5;
        int d2 = dy*dy + dx*dx;
        int rank = 0;
        for (int j = 0; j < 121; j++) {
            int ey = j / 11 - 5, ex = j % 11 - 5;
            int e2 = ey*ey + ex*ex;
            rank += (e2 < d2) || (e2 == d2 && j < i);
        }
        t.off[rank] = (dy + 5) * WTW + (dx + 5);
        ds[rank]    = (float)d2;
    }
    int g = 0;
    t.gid[0] = 0; t.gd2[0] = ds[0];
    for (int r = 1; r < 121; r++) {
        if (ds[r] != ds[r-1]) { g++; t.gd2[g] = ds[r]; }
        t.gid[r] = g;
    }
    return t;
}
constexpr NbrTbl TBL = make_tbl();

// Node 1: control-slot zeroing + per-image chunk sum partials (fixed order).
__global__ __launch_bounds__(256) void k_sums(const float* __restrict__ in, float* __restrict__ ws) {
    __shared__ float sh4[4];
    if (blockIdx.x == 0 && threadIdx.x < 64) ws[threadIdx.x] = 0.f;
    int j = blockIdx.x;
    int idx = j / 49, chunk = j % 49;
    int cc = idx >> 2, bb = idx & 3;
    const float4* w4 = (const float4*)(in + (size_t)(bb*3 + cc) * GN);
    float4 v = w4[chunk*256 + threadIdx.x];
    float s = v.x + v.y + v.z + v.w;
    #pragma unroll
    for (int off = 32; off; off >>= 1) s += __shfl_down(s, off);
    if ((threadIdx.x & 63) == 0) sh4[threadIdx.x >> 6] = s;
    __syncthreads();
    if (threadIdx.x == 0) ws[WS_SUMP + j] = sh4[0] + sh4[1] + sh4[2] + sh4[3];
}

// Node 2: DTM + 3x3 min/max + global minmax + minima compaction per 28x14 tile.
// Two F-points per thread (rows fy0 and fy0+8) -> 2 independent ds_read/add
// streams per thread to hide LDS latency (R7 was serialized at VGPR_Count=32).
__global__ __launch_bounds__(256) void k_dtm(const float* __restrict__ in, float* __restrict__ ws) {
    __shared__ float wt[WTN];
    __shared__ float Ft[16*32];        // 16 rows x stride 32 (cols 0..29 valid)
    __shared__ float sb[416], sd[416];
    __shared__ float smn[4], smx[4];
    __shared__ float sbound;
    __shared__ int lcnt, gbase;
    const int tid = threadIdx.x;

    int tile_id = blockIdx.x;
    int idx  = tile_id / TPI;
    int trem = tile_id % TPI;
    int tyi = trem / TILES_X, txi = trem % TILES_X;
    int gy = tyi*14, gx = txi*28;      // interior origin
    int cc = idx >> 2, bb = idx & 3;
    const float* w = in + (size_t)(bb*3 + cc) * GN;

    // bound = 0.05 * sum(image) from 49 partials (fixed-order -> identical per image)
    if (tid < 64) {
        float p = (tid < 49) ? ws[WS_SUMP + idx*49 + tid] : 0.f;
        #pragma unroll
        for (int off = 32; off; off >>= 1) p += __shfl_down(p, off);
        if (tid == 0) { sbound = 0.05f * p; lcnt = 0; }
    }

    // stage border-clamped w halo tile 26x40
    int wy0 = gy - 6, wx0 = gx - 6;
    for (int i = tid; i < WTN; i += 256) {
        int r = i / WTW, q = i % WTW;
        int yy = wy0 + r; yy = yy < 0 ? 0 : (yy > GH-1 ? GH-1 : yy);
        int xx = wx0 + q; xx = xx < 0 ? 0 : (xx > GW-1 ? GW-1 : xx);
        wt[i] = w[yy*GW + xx];
    }
    __syncthreads();

    float bound = sbound;
    int fx = tid & 31, fy0 = tid >> 5, fy1 = fy0 + 8;
    float fA = 0.f, fB = 0.f;
    float mnv = INFINITY, mxv = -INFINITY;
    if (fx < 30) {
        // F point = interior-1 + (fy,fx); halo points computed at CLAMPED center
        int px0 = gx - 1 + fx; int pxc = px0 < 0 ? 0 : (px0 > GW-1 ? GW-1 : px0);
        int pyA = gy - 1 + fy0; int pyAc = pyA < 0 ? 0 : (pyA > GH-1 ? GH-1 : pyA);
        int pyB = gy - 1 + fy1; int pyBc = pyB < 0 ? 0 : (pyB > GH-1 ? GH-1 : pyB);
        const float* basepA = wt + (pyAc - wy0 - 5)*WTW + (pxc - wx0 - 5);
        const float* basepB = wt + (pyBc - wy0 - 5)*WTW + (pxc - wx0 - 5);
        float gA[NG], gB[NG];
        #pragma unroll
        for (int g = 0; g < NG; g++) { gA[g] = 0.f; gB[g] = 0.f; }
        #pragma unroll
        for (int j = 0; j < 121; j++) {
            float a = basepA[TBL.off[j]];
            float b2 = basepB[TBL.off[j]];
            gA[TBL.gid[j]] += a;
            gB[TBL.gid[j]] += b2;
        }
        float cumA = 0.f, accA = 0.f, cumB = 0.f, accB = 0.f;
        #pragma unroll
        for (int g = 0; g < NG; g++) {
            float vA = bound - cumA;
            vA = vA < 0.f ? 0.f : vA;
            vA = vA > gA[g] ? gA[g] : vA;
            accA = fmaf(vA, TBL.gd2[g], accA);
            cumA += gA[g];
            float vB = bound - cumB;
            vB = vB < 0.f ? 0.f : vB;
            vB = vB > gB[g] ? gB[g] : vB;
            accB = fmaf(vB, TBL.gd2[g], accB);
            cumB += gB[g];
        }
        fA = sqrtf(accA / bound + 1e-12f);
        fB = sqrtf(accB / bound + 1e-12f);
        Ft[fy0*32 + fx] = fA;
        Ft[fy1*32 + fx] = fB;
        mnv = fminf(fA, fB); mxv = fmaxf(fA, fB);   // halo pts are clamped dups -> safe
    }
    #pragma unroll
    for (int off = 32; off; off >>= 1) {
        mnv = fminf(mnv, __shfl_down(mnv, off));
        mxv = fmaxf(mxv, __shfl_down(mxv, off));
    }
    if ((tid & 63) == 0) { smn[tid>>6] = mnv; smx[tid>>6] = mxv; }
    __syncthreads();                   // Ft complete + smn/smx ready
    if (tid == 0) {
        float bm = fminf(fminf(smn[0], smn[1]), fminf(smn[2], smn[3]));
        float bX = fmaxf(fmaxf(smx[0], smx[1]), fmaxf(smx[2], smx[3]));
        atomicMax((unsigned int*)&ws[WS_MM + 2*idx], ~__float_as_uint(bm));
        atomicMax((unsigned int*)&ws[WS_MM + 2*idx + 1], __float_as_uint(bX));
    }

    // 3x3 is_min / death on 28x14 interior (both points; exact tiling, no tail)
    if (fx >= 1 && fx <= 28) {
        if (fy0 >= 1) {                // point A interior rows fy0 in 1..7
            const float* Fc = Ft + (fy0-1)*32 + (fx-1);
            float mn = fA, mx = fA;
            #pragma unroll
            for (int dy = 0; dy < 3; dy++)
                #pragma unroll
                for (int dx = 0; dx < 3; dx++) {
                    float v = Fc[dy*32 + dx];
                    mn = fminf(mn, v); mx = fmaxf(mx, v);
                }
            if (fA <= mn) {
                int s = atomicAdd(&lcnt, 1);
                sb[s] = fA; sd[s] = mx;
            }
        }
        if (fy1 <= 14) {               // point B interior rows fy1 in 8..14
            const float* Fc = Ft + (fy1-1)*32 + (fx-1);
            float mn = fB, mx = fB;
            #pragma unroll
            for (int dy = 0; dy < 3; dy++)
                #pragma unroll
                for (int dx = 0; dx < 3; dx++) {
                    float v = Fc[dy*32 + dx];
                    mn = fminf(mn, v); mx = fmaxf(mx, v);
                }
            if (fB <= mn) {
                int s = atomicAdd(&lcnt, 1);
                sb[s] = fB; sd[s] = mx;
            }
        }
    }
    __syncthreads();
    if (tid == 0) gbase = atomicAdd((int*)ws + WS_CTR + idx, lcnt);
    __syncthreads();
    int n = lcnt, gb = gbase;
    float2* list = (float2*)(ws + WS_LIST) + (size_t)idx * CAP;
    for (int i = tid; i < n; i += 256)
        if (gb + i < CAP) list[gb + i] = make_float2(sb[i], sd[i]);
}

// Node 3: top-2 landscape per (image,t) + ticket -> last block runs the heads.
__global__ __launch_bounds__(256) void k_top2head(
        const float* __restrict__ W1, const float* __restrict__ b1,
        const float* __restrict__ W2, const float* __restrict__ b2,
        const float* __restrict__ W3, const float* __restrict__ b3,
        const float* __restrict__ fcw, const float* __restrict__ fcb,
        float* __restrict__ ws, float* __restrict__ out)
{
    __shared__ float r0s[4], r1s[4];
    __shared__ int tick;
    const int tid = threadIdx.x;
    {
        int jb = blockIdx.x;
        int idx = jb / NT, t = jb % NT;
        int nm = ((const int*)ws)[WS_CTR + idx]; if (nm > CAP) nm = CAP;
        float tmin = __uint_as_float(~((const unsigned int*)ws)[WS_MM + 2*idx]);
        float tmax = __uint_as_float( ((const unsigned int*)ws)[WS_MM + 2*idx + 1]);
        float tss = tmin + (tmax - tmin) * ((float)t / 24.0f);
        const float2* list = (const float2*)(ws + WS_LIST) + (size_t)idx * CAP;
        float a0 = 0.f, a1 = 0.f;
        for (int i = tid; i < nm; i += 256) {
            float2 p = list[i];
            float v = fmaxf(fminf(tss - p.x, p.y - tss), 0.f);
            float n0 = fmaxf(a0, v);
            a1 = fmaxf(a1, fminf(a0, v));
            a0 = n0;
        }
        #pragma unroll
        for (int off = 32; off; off >>= 1) {
            float b0 = __shfl_down(a0, off);
            float b1 = __shfl_down(a1, off);
            float n0 = fmaxf(a0, b0);
            a1 = fmaxf(fminf(a0, b0), fmaxf(a1, b1));
            a0 = n0;
        }
        if ((tid & 63) == 0) { r0s[tid>>6] = a0; r1s[tid>>6] = a1; }
        __syncthreads();
        if (tid == 0) {
            float c0 = r0s[0], c1 = r1s[0];
            #pragma unroll
            for (int wv = 1; wv < 4; wv++) {
                float b0 = r0s[wv], b1 = r1s[wv];
                float n0 = fmaxf(c0, b0);
                c1 = fmaxf(fminf(c0, b0), fmaxf(c1, b1));
                c0 = n0;
            }
            // agent-scope stores: lam must be coherent across XCDs for the head block
            __hip_atomic_store(&ws[WS_LAM + (size_t)idx*50 + t*2],     c0,
                               __ATOMIC_RELAXED, __HIP_MEMORY_SCOPE_AGENT);
            __hip_atomic_store(&ws[WS_LAM + (size_t)idx*50 + t*2 + 1], c1,
                               __ATOMIC_RELAXED, __HIP_MEMORY_SCOPE_AGENT);
        }
    }
    __threadfence();                              // release
    __syncthreads();
    if (tid == 0) tick = atomicAdd((int*)ws + WS_TICK, 1);
    __syncthreads();
    if (tick != 299) return;                      // last-arriving block runs the heads
    __threadfence();                              // acquire

    __shared__ float lamS[600];
    __shared__ float xsh[600];
    for (int i = tid; i < 600; i += 256)
        lamS[i] = __hip_atomic_load(&ws[WS_LAM + i], __ATOMIC_RELAXED,
                                    __HIP_MEMORY_SCOPE_AGENT);
    __syncthreads();
    for (int j = tid; j < 600; j += 256) {
        int b = j / 150, r = j % 150, c = r / 50, o = r % 50;
        const float* Wc = (c == 0) ? W1 : (c == 1) ? W2 : W3;
        const float* bc = (c == 0) ? b1 : (c == 1) ? b2 : b3;
        const float* lam = lamS + (c*4 + b) * 50;
        float acc = bc[o];
        for (int f2 = 0; f2 < 50; f2++) acc += lam[f2] * Wc[o*50 + f2];
        xsh[j] = acc;
    }
    __syncthreads();
    if (tid < 150) {                     // signal = sum_b |x|
        float s = 0.f;
        for (int b = 0; b < 4; b++) s += fabsf(xsh[b*150 + tid]);
        out[28 + tid] = s;
    }
    if (tid < 28) {                      // output = relu(x) @ fc_w.T + fc_b
        int b = tid / 7, o = tid % 7;
        float acc = fcb[o];
        for (int j = 0; j < 150; j++) acc += fmaxf(xsh[b*150 + j], 0.f) * fcw[o*150 + j];
        out[b*7 + o] = acc;
    }
}

extern "C" void kernel_launch(void* const* d_in, const int* in_sizes, int n_in,
                              void* d_out, int out_size, void* d_ws, size_t ws_size,
                              hipStream_t stream) {
    const float* in  = (const float*)d_in[0];
    const float* W1  = (const float*)d_in[1];
    const float* b1  = (const float*)d_in[2];
    const float* W2  = (const float*)d_in[3];
    const float* b2  = (const float*)d_in[4];
    const float* W3  = (const float*)d_in[5];
    const float* b3  = (const float*)d_in[6];
    const float* fcw = (const float*)d_in[7];
    const float* fcb = (const float*)d_in[8];
    float* ws  = (float*)d_ws;
    float* out = (float*)d_out;

    k_sums    <<<NSUMJ,  256, 0, stream>>>(in, ws);
    k_dtm     <<<NTILES, 256, 0, stream>>>(in, ws);
    k_top2head<<<300,    256, 0, stream>>>(W1, b1, W2, b2, W3, b3, fcw, fcb, ws, out);
}

// Round 9
// 142.168 us; speedup vs baseline: 2.9059x; 1.0308x over previous
//
#include <hip/hip_runtime.h>
#include <math.h>

#define GH 224
#define GW 224
#define GN (GH*GW)          // 50176
#define NT 25
#define NG 20               // distinct d2 values in 11x11 window
#define CAP 24576           // per-image (birth,death) list capacity
#define TILES_X 8           // 28 px wide  (8*28 = 224 exact)
#define TILES_Y 16          // 14 px tall  (16*14 = 224 exact)
#define TPI (TILES_X*TILES_Y)   // 128 tiles per image
#define NTILES (12*TPI)         // 1536
#define NSUMJ 588               // 12 images * 49 chunks of 1024 px
#define WTW 41              // w-tile stride (40 cols used; odd stride -> all 32 banks)
#define WTH 26              // (14+2)+10 tall
#define WTN (WTW*WTH)       // 1066

// ws float offsets:
// [16..40)   per-idx (mn_invbits, mx_bits) via uint atomicMax
// [48..60)   per-idx minima-list counters (int)
// [60]       ticket (int)
// [64..664)  lam[12][50]
// [700..1288) 588 per-chunk sum partials
// [2048..)   per-image lists: float2[CAP] each
#define WS_MM   16
#define WS_CTR  48
#define WS_TICK 60
#define WS_LAM  64
#define WS_SUMP 700
#define WS_LIST 2048

// Group table: group id per (dy,dx) = rank of its d2 among the 20 distinct d2
// values, ascending. Equal-d2 sets in ascending order == stable-argsort run
// partition (HW-verified R4/R6/R7/R8: sequential clip-fill over an equal-d2 run
// == one clip of the run sum).
struct GrpTbl { int g[11][11]; float gd2[NG]; };
constexpr GrpTbl make_g() {
    GrpTbl t{};
    int n = 0;
    for (int v = 0; v <= 50; v++) {
        bool found = false;
        for (int dy = -5; dy <= 5 && !found; dy++)
            for (int dx = -5; dx <= 5 && !found; dx++)
                if (dy*dy + dx*dx == v) found = true;
        if (found) { t.gd2[n] = (float)v; n++; }
    }
    for (int dy = 0; dy < 11; dy++)
        for (int dx = 0; dx < 11; dx++) {
            int d2 = (dy-5)*(dy-5) + (dx-5)*(dx-5);
            for (int k = 0; k < NG; k++)
                if ((float)d2 == t.gd2[k]) t.g[dy][dx] = k;
        }
    return t;
}
constexpr GrpTbl TG = make_g();

// Node 1: control-slot zeroing + per-image chunk sum partials (fixed order).
__global__ __launch_bounds__(256) void k_sums(const float* __restrict__ in, float* __restrict__ ws) {
    __shared__ float sh4[4];
    if (blockIdx.x == 0 && threadIdx.x < 64) ws[threadIdx.x] = 0.f;
    int j = blockIdx.x;
    int idx = j / 49, chunk = j % 49;
    int cc = idx >> 2, bb = idx & 3;
    const float4* w4 = (const float4*)(in + (size_t)(bb*3 + cc) * GN);
    float4 v = w4[chunk*256 + threadIdx.x];
    float s = v.x + v.y + v.z + v.w;
    #pragma unroll
    for (int off = 32; off; off >>= 1) s += __shfl_down(s, off);
    if ((threadIdx.x & 63) == 0) sh4[threadIdx.x >> 6] = s;
    __syncthreads();
    if (threadIdx.x == 0) ws[WS_SUMP + j] = sh4[0] + sh4[1] + sh4[2] + sh4[3];
}

// Node 2: DTM + 3x3 min/max + minima compaction per 28x14 tile.
// Each thread: a HORIZONTAL PAIR of F-points (fx0, fx0+1). Union window =
// 11 rows x 12 cols = 132 ds_reads for 2 points (vs 242); reads batched
// per-row for load independence, each read feeds both accumulators.
__global__ __launch_bounds__(256) void k_dtm(const float* __restrict__ in, float* __restrict__ ws) {
    __shared__ float wt[WTN];
    __shared__ float Ft[16*32];        // 16 rows x stride 32 (cols 0..29 valid)
    __shared__ float sb[416], sd[416];
    __shared__ float smn[4], smx[4];
    __shared__ float sbound;
    __shared__ int lcnt, gbase;
    const int tid = threadIdx.x;

    int tile_id = blockIdx.x;
    int idx  = tile_id / TPI;
    int trem = tile_id % TPI;
    int tyi = trem / TILES_X, txi = trem % TILES_X;
    int gy = tyi*14, gx = txi*28;      // interior origin
    int cc = idx >> 2, bb = idx & 3;
    const float* w = in + (size_t)(bb*3 + cc) * GN;

    // bound = 0.05 * sum(image) from 49 partials (fixed-order -> identical per image)
    if (tid < 64) {
        float p = (tid < 49) ? ws[WS_SUMP + idx*49 + tid] : 0.f;
        #pragma unroll
        for (int off = 32; off; off >>= 1) p += __shfl_down(p, off);
        if (tid == 0) { sbound = 0.05f * p; lcnt = 0; }
    }

    // stage border-clamped w halo tile 26 x (40 used / 41 stride)
    int wy0 = gy - 6, wx0 = gx - 6;
    for (int i = tid; i < WTN; i += 256) {
        int r = i / WTW, q = i % WTW;
        int yy = wy0 + r; yy = yy < 0 ? 0 : (yy > GH-1 ? GH-1 : yy);
        int xx = wx0 + q; xx = xx < 0 ? 0 : (xx > GW-1 ? GW-1 : xx);
        wt[i] = w[yy*GW + xx];
    }
    __syncthreads();

    const bool act = tid < 240;        // 16 F-rows x 15 col-pairs
    int fy  = act ? tid / 15 : 0;
    int fxp = act ? tid % 15 : 0;
    int fx0 = fxp*2, fx1 = fx0 + 1;
    float bound = sbound;
    float fA = 0.f, fB = 0.f;
    {
        // clamped centers (halo F-points computed at CLAMPED coords)
        int pyA = gy - 1 + fy;  int pyc  = pyA < 0 ? 0 : (pyA > GH-1 ? GH-1 : pyA);
        int pxA = gx - 1 + fx0; int pxAc = pxA < 0 ? 0 : (pxA > GW-1 ? GW-1 : pxA);
        int pxB = gx - 1 + fx1; int pxBc = pxB < 0 ? 0 : (pxB > GW-1 ? GW-1 : pxB);
        int dlt = pxBc - pxAc;         // 1 interior, 0 at image border (windows equal)
        const float* base = wt + (pyc - wy0 - 5)*WTW + (pxAc - wx0 - 5);
        float gA[NG], gB[NG];
        #pragma unroll
        for (int g = 0; g < NG; g++) { gA[g] = 0.f; gB[g] = 0.f; }
        #pragma unroll
        for (int r = 0; r < 11; r++) {
            float row[12];
            #pragma unroll
            for (int c = 0; c < 12; c++) row[c] = base[r*WTW + c];
            #pragma unroll
            for (int c = 0; c < 11; c++) gA[TG.g[r][c]] += row[c];     // A: dx=c-5
            #pragma unroll
            for (int c = 1; c < 12; c++) gB[TG.g[r][c-1]] += row[c];   // B: dx=c-6 (dlt=1)
        }
        float cumA = 0.f, accA = 0.f, cumB = 0.f, accB = 0.f;
        #pragma unroll
        for (int g = 0; g < NG; g++) {
            float vA = bound - cumA;
            vA = vA < 0.f ? 0.f : vA;
            vA = vA > gA[g] ? gA[g] : vA;
            accA = fmaf(vA, TG.gd2[g], accA);
            cumA += gA[g];
            float vB = bound - cumB;
            vB = vB < 0.f ? 0.f : vB;
            vB = vB > gB[g] ? gB[g] : vB;
            accB = fmaf(vB, TG.gd2[g], accB);
            cumB += gB[g];
        }
        fA = sqrtf(accA / bound + 1e-12f);
        fB = (dlt == 0) ? fA : sqrtf(accB / bound + 1e-12f);
    }
    float mnv = INFINITY, mxv = -INFINITY;
    if (act) {
        Ft[fy*32 + fx0] = fA;
        Ft[fy*32 + fx1] = fB;
        mnv = fminf(fA, fB); mxv = fmaxf(fA, fB);   // halo pts are clamped dups -> safe
    }
    #pragma unroll
    for (int off = 32; off; off >>= 1) {
        mnv = fminf(mnv, __shfl_down(mnv, off));
        mxv = fmaxf(mxv, __shfl_down(mxv, off));
    }
    if ((tid & 63) == 0) { smn[tid>>6] = mnv; smx[tid>>6] = mxv; }
    __syncthreads();                   // Ft complete + smn/smx ready
    if (tid == 0) {
        float bm = fminf(fminf(smn[0], smn[1]), fminf(smn[2], smn[3]));
        float bX = fmaxf(fmaxf(smx[0], smx[1]), fmaxf(smx[2], smx[3]));
        atomicMax((unsigned int*)&ws[WS_MM + 2*idx], ~__float_as_uint(bm));
        atomicMax((unsigned int*)&ws[WS_MM + 2*idx + 1], __float_as_uint(bX));
    }

    // 3x3 is_min / death on 28x14 interior (F rows 1..14, cols 1..28)
    if (act && fy >= 1 && fy <= 14) {
        if (fx0 >= 1) {
            const float* Fc = Ft + (fy-1)*32 + (fx0-1);
            float mn = fA, mx = fA;
            #pragma unroll
            for (int dy = 0; dy < 3; dy++)
                #pragma unroll
                for (int dx = 0; dx < 3; dx++) {
                    float v = Fc[dy*32 + dx];
                    mn = fminf(mn, v); mx = fmaxf(mx, v);
                }
            if (fA <= mn) {
                int s = atomicAdd(&lcnt, 1);
                sb[s] = fA; sd[s] = mx;
            }
        }
        if (fx1 <= 28) {
            const float* Fc = Ft + (fy-1)*32 + (fx1-1);
            float mn = fB, mx = fB;
            #pragma unroll
            for (int dy = 0; dy < 3; dy++)
                #pragma unroll
                for (int dx = 0; dx < 3; dx++) {
                    float v = Fc[dy*32 + dx];
                    mn = fminf(mn, v); mx = fmaxf(mx, v);
                }
            if (fB <= mn) {
                int s = atomicAdd(&lcnt, 1);
                sb[s] = fB; sd[s] = mx;
            }
        }
    }
    __syncthreads();
    if (tid == 0) gbase = atomicAdd((int*)ws + WS_CTR + idx, lcnt);
    __syncthreads();
    int n = lcnt, gb = gbase;
    float2* list = (float2*)(ws + WS_LIST) + (size_t)idx * CAP;
    for (int i = tid; i < n; i += 256)
        if (gb + i < CAP) list[gb + i] = make_float2(sb[i], sd[i]);
}

// Node 3: top-2 landscape per (image,t) + ticket -> last block runs the heads.
__global__ __launch_bounds__(256) void k_top2head(
        const float* __restrict__ W1, const float* __restrict__ b1,
        const float* __restrict__ W2, const float* __restrict__ b2,
        const float* __restrict__ W3, const float* __restrict__ b3,
        const float* __restrict__ fcw, const float* __restrict__ fcb,
        float* __restrict__ ws, float* __restrict__ out)
{
    __shared__ float r0s[4], r1s[4];
    __shared__ int tick;
    const int tid = threadIdx.x;
    {
        int jb = blockIdx.x;
        int idx = jb / NT, t = jb % NT;
        int nm = ((const int*)ws)[WS_CTR + idx]; if (nm > CAP) nm = CAP;
        float tmin = __uint_as_float(~((const unsigned int*)ws)[WS_MM + 2*idx]);
        float tmax = __uint_as_float( ((const unsigned int*)ws)[WS_MM + 2*idx + 1]);
        float tss = tmin + (tmax - tmin) * ((float)t / 24.0f);
        const float2* list = (const float2*)(ws + WS_LIST) + (size_t)idx * CAP;
        float a0 = 0.f, a1 = 0.f;
        for (int i = tid; i < nm; i += 256) {
            float2 p = list[i];
            float v = fmaxf(fminf(tss - p.x, p.y - tss), 0.f);
            float n0 = fmaxf(a0, v);
            a1 = fmaxf(a1, fminf(a0, v));
            a0 = n0;
        }
        #pragma unroll
        for (int off = 32; off; off >>= 1) {
            float b0 = __shfl_down(a0, off);
            float b1 = __shfl_down(a1, off);
            float n0 = fmaxf(a0, b0);
            a1 = fmaxf(fminf(a0, b0), fmaxf(a1, b1));
            a0 = n0;
        }
        if ((tid & 63) == 0) { r0s[tid>>6] = a0; r1s[tid>>6] = a1; }
        __syncthreads();
        if (tid == 0) {
            float c0 = r0s[0], c1 = r1s[0];
            #pragma unroll
            for (int wv = 1; wv < 4; wv++) {
                float b0 = r0s[wv], b1 = r1s[wv];
                float n0 = fmaxf(c0, b0);
                c1 = fmaxf(fminf(c0, b0), fmaxf(c1, b1));
                c0 = n0;
            }
            // agent-scope stores: lam must be coherent across XCDs for the head block
            __hip_atomic_store(&ws[WS_LAM + (size_t)idx*50 + t*2],     c0,
                               __ATOMIC_RELAXED, __HIP_MEMORY_SCOPE_AGENT);
            __hip_atomic_store(&ws[WS_LAM + (size_t)idx*50 + t*2 + 1], c1,
                               __ATOMIC_RELAXED, __HIP_MEMORY_SCOPE_AGENT);
        }
    }
    __threadfence();                              // release
    __syncthreads();
    if (tid == 0) tick = atomicAdd((int*)ws + WS_TICK, 1);
    __syncthreads();
    if (tick != 299) return;                      // last-arriving block runs the heads
    __threadfence();                              // acquire

    __shared__ float lamS[600];
    __shared__ float xsh[600];
    for (int i = tid; i < 600; i += 256)
        lamS[i] = __hip_atomic_load(&ws[WS_LAM + i], __ATOMIC_RELAXED,
                                    __HIP_MEMORY_SCOPE_AGENT);
    __syncthreads();
    for (int j = tid; j < 600; j += 256) {
        int b = j / 150, r = j % 150, c = r / 50, o = r % 50;
        const float* Wc = (c == 0) ? W1 : (c == 1) ? W2 : W3;
        const float* bc = (c == 0) ? b1 : (c == 1) ? b2 : b3;
        const float* lam = lamS + (c*4 + b) * 50;
        float acc = bc[o];
        for (int f2 = 0; f2 < 50; f2++) acc += lam[f2] * Wc[o*50 + f2];
        xsh[j] = acc;
    }
    __syncthreads();
    if (tid < 150) {                     // signal = sum_b |x|
        float s = 0.f;
        for (int b = 0; b < 4; b++) s += fabsf(xsh[b*150 + tid]);
        out[28 + tid] = s;
    }
    if (tid < 28) {                      // output = relu(x) @ fc_w.T + fc_b
        int b = tid / 7, o = tid % 7;
        float acc = fcb[o];
        for (int j = 0; j < 150; j++) acc += fmaxf(xsh[b*150 + j], 0.f) * fcw[o*150 + j];
        out[b*7 + o] = acc;
    }
}

extern "C" void kernel_launch(void* const* d_in, const int* in_sizes, int n_in,
                              void* d_out, int out_size, void* d_ws, size_t ws_size,
                              hipStream_t stream) {
    const float* in  = (const float*)d_in[0];
    const float* W1  = (const float*)d_in[1];
    const float* b1  = (const float*)d_in[2];
    const float* W2  = (const float*)d_in[3];
    const float* b2  = (const float*)d_in[4];
    const float* W3  = (const float*)d_in[5];
    const float* b3  = (const float*)d_in[6];
    const float* fcw = (const float*)d_in[7];
    const float* fcb = (const float*)d_in[8];
    float* ws  = (float*)d_ws;
    float* out = (float*)d_out;

    k_sums    <<<NSUMJ,  256, 0, stream>>>(in, ws);
    k_dtm     <<<NTILES, 256, 0, stream>>>(in, ws);
    k_top2head<<<300,    256, 0, stream>>>(W1, b1, W2, b2, W3, b3, fcw, fcb, ws, out);
}

// Round 10
// 127.151 us; speedup vs baseline: 3.2491x; 1.1181x over previous
//
#include <hip/hip_runtime.h>
#include <math.h>

#define GH 224
#define GW 224
#define GN (GH*GW)          // 50176
#define NT 25
#define NG 20               // distinct d2 values in 11x11 window
#define CAP 24576           // per-image (birth,death) list capacity (16 segs x 1536)
#define SEGN 16
#define SEGCAP 1536
#define TILES_X 8           // 28 px wide  (8*28 = 224 exact)
#define TILES_Y 16          // 14 px tall  (16*14 = 224 exact)
#define TPI (TILES_X*TILES_Y)   // 128 tiles per image
#define NTILES (12*TPI)         // 1536
#define NSUMJ 588               // 12 images * 49 chunks of 1024 px
#define WTW 41              // w-tile stride (40 cols used; odd stride -> all 32 banks)
#define WTH 26              // (14+2)+10 tall
#define WTN (WTW*WTH)       // 1066

// ws float offsets:
// [16..784)    minmax replicas: per image 32 x (mn_invbits, mx_bits), uint atomicMax
// [784..976)   per-(image,segment) minima counters (12*16 ints)
// [976]        ticket (int)
// [1024..1624) lam[12][50]
// [1664..2252) 588 per-chunk sum partials
// [4096..)     per-image lists: float2[CAP], segmented 16 x 1536
#define WS_MM   16
#define WS_CTR  784
#define WS_TICK 976
#define WS_LAM  1024
#define WS_SUMP 1664
#define WS_LIST 4096

// Group table: group id per (dy,dx) = rank of its d2 among the 20 distinct d2
// values, ascending == stable-argsort run partition (HW-verified R4..R9:
// sequential clip-fill over an equal-d2 run == one clip of the run sum).
struct GrpTbl { int g[11][11]; float gd2[NG]; };
constexpr GrpTbl make_g() {
    GrpTbl t{};
    int n = 0;
    for (int v = 0; v <= 50; v++) {
        bool found = false;
        for (int dy = -5; dy <= 5 && !found; dy++)
            for (int dx = -5; dx <= 5 && !found; dx++)
                if (dy*dy + dx*dx == v) found = true;
        if (found) { t.gd2[n] = (float)v; n++; }
    }
    for (int dy = 0; dy < 11; dy++)
        for (int dx = 0; dx < 11; dx++) {
            int d2 = (dy-5)*(dy-5) + (dx-5)*(dx-5);
            for (int k = 0; k < NG; k++)
                if ((float)d2 == t.gd2[k]) t.g[dy][dx] = k;
        }
    return t;
}
constexpr GrpTbl TG = make_g();

// Node 1: zero ctl region [0..1024) (disjoint float4 per block) + sum partials.
__global__ __launch_bounds__(256) void k_sums(const float* __restrict__ in, float* __restrict__ ws) {
    __shared__ float sh4[4];
    int j = blockIdx.x;
    if (j < 256 && threadIdx.x == 0)
        ((float4*)ws)[j] = make_float4(0.f, 0.f, 0.f, 0.f);
    int idx = j / 49, chunk = j % 49;
    int cc = idx >> 2, bb = idx & 3;
    const float4* w4 = (const float4*)(in + (size_t)(bb*3 + cc) * GN);
    float4 v = w4[chunk*256 + threadIdx.x];
    float s = v.x + v.y + v.z + v.w;
    #pragma unroll
    for (int off = 32; off; off >>= 1) s += __shfl_down(s, off);
    if ((threadIdx.x & 63) == 0) sh4[threadIdx.x >> 6] = s;
    __syncthreads();
    if (threadIdx.x == 0) ws[WS_SUMP + j] = sh4[0] + sh4[1] + sh4[2] + sh4[3];
}

// Node 2: DTM + 3x3 min/max + minima compaction per 28x14 tile.
// Horizontal-pair F-points per thread (R9). Contended atomics replaced by
// replicas: minmax rep = tile&31 (4 blocks/rep), list segment = tile&15
// (8 blocks/seg) -- kills the same-address cross-XCD atomic queue (R10 theory).
__global__ __launch_bounds__(256) void k_dtm(const float* __restrict__ in, float* __restrict__ ws) {
    __shared__ float wt[WTN];
    __shared__ float Ft[16*32];        // 16 rows x stride 32 (cols 0..29 valid)
    __shared__ float sb[416], sd[416];
    __shared__ float smn[4], smx[4];
    __shared__ float sbound;
    __shared__ int lcnt, gbase;
    const int tid = threadIdx.x;

    int tile_id = blockIdx.x;
    int idx  = tile_id / TPI;
    int trem = tile_id % TPI;
    int tyi = trem / TILES_X, txi = trem % TILES_X;
    int gy = tyi*14, gx = txi*28;      // interior origin
    int cc = idx >> 2, bb = idx & 3;
    const float* w = in + (size_t)(bb*3 + cc) * GN;
    int rep = trem & 31;               // minmax replica
    int seg = trem & 15;               // list segment

    // bound = 0.05 * sum(image) from 49 partials (fixed-order -> identical per image)
    if (tid < 64) {
        float p = (tid < 49) ? ws[WS_SUMP + idx*49 + tid] : 0.f;
        #pragma unroll
        for (int off = 32; off; off >>= 1) p += __shfl_down(p, off);
        if (tid == 0) { sbound = 0.05f * p; lcnt = 0; }
    }

    // stage border-clamped w halo tile 26 x (40 used / 41 stride)
    int wy0 = gy - 6, wx0 = gx - 6;
    for (int i = tid; i < WTN; i += 256) {
        int r = i / WTW, q = i % WTW;
        int yy = wy0 + r; yy = yy < 0 ? 0 : (yy > GH-1 ? GH-1 : yy);
        int xx = wx0 + q; xx = xx < 0 ? 0 : (xx > GW-1 ? GW-1 : xx);
        wt[i] = w[yy*GW + xx];
    }
    __syncthreads();

    const bool act = tid < 240;        // 16 F-rows x 15 col-pairs
    int fy  = act ? tid / 15 : 0;
    int fxp = act ? tid % 15 : 0;
    int fx0 = fxp*2, fx1 = fx0 + 1;
    float bound = sbound;
    float fA = 0.f, fB = 0.f;
    {
        int pyA = gy - 1 + fy;  int pyc  = pyA < 0 ? 0 : (pyA > GH-1 ? GH-1 : pyA);
        int pxA = gx - 1 + fx0; int pxAc = pxA < 0 ? 0 : (pxA > GW-1 ? GW-1 : pxA);
        int pxB = gx - 1 + fx1; int pxBc = pxB < 0 ? 0 : (pxB > GW-1 ? GW-1 : pxB);
        int dlt = pxBc - pxAc;         // 1 interior, 0 at image border (windows equal)
        const float* base = wt + (pyc - wy0 - 5)*WTW + (pxAc - wx0 - 5);
        float gA[NG], gB[NG];
        #pragma unroll
        for (int g = 0; g < NG; g++) { gA[g] = 0.f; gB[g] = 0.f; }
        #pragma unroll
        for (int r = 0; r < 11; r++) {
            float row[12];
            #pragma unroll
            for (int c = 0; c < 12; c++) row[c] = base[r*WTW + c];
            #pragma unroll
            for (int c = 0; c < 11; c++) gA[TG.g[r][c]] += row[c];     // A: dx=c-5
            #pragma unroll
            for (int c = 1; c < 12; c++) gB[TG.g[r][c-1]] += row[c];   // B: dx=c-6
        }
        float cumA = 0.f, accA = 0.f, cumB = 0.f, accB = 0.f;
        #pragma unroll
        for (int g = 0; g < NG; g++) {
            float vA = bound - cumA;
            vA = vA < 0.f ? 0.f : vA;
            vA = vA > gA[g] ? gA[g] : vA;
            accA = fmaf(vA, TG.gd2[g], accA);
            cumA += gA[g];
            float vB = bound - cumB;
            vB = vB < 0.f ? 0.f : vB;
            vB = vB > gB[g] ? gB[g] : vB;
            accB = fmaf(vB, TG.gd2[g], accB);
            cumB += gB[g];
        }
        fA = sqrtf(accA / bound + 1e-12f);
        fB = (dlt == 0) ? fA : sqrtf(accB / bound + 1e-12f);
    }
    float mnv = INFINITY, mxv = -INFINITY;
    if (act) {
        Ft[fy*32 + fx0] = fA;
        Ft[fy*32 + fx1] = fB;
        mnv = fminf(fA, fB); mxv = fmaxf(fA, fB);   // halo pts are clamped dups -> safe
    }
    #pragma unroll
    for (int off = 32; off; off >>= 1) {
        mnv = fminf(mnv, __shfl_down(mnv, off));
        mxv = fmaxf(mxv, __shfl_down(mxv, off));
    }
    if ((tid & 63) == 0) { smn[tid>>6] = mnv; smx[tid>>6] = mxv; }
    __syncthreads();                   // Ft complete + smn/smx ready
    if (tid == 0) {
        float bm = fminf(fminf(smn[0], smn[1]), fminf(smn[2], smn[3]));
        float bX = fmaxf(fmaxf(smx[0], smx[1]), fmaxf(smx[2], smx[3]));
        // replicated (4 blocks per replica slot -> negligible queueing)
        atomicMax((unsigned int*)&ws[WS_MM + (idx*32 + rep)*2],     ~__float_as_uint(bm));
        atomicMax((unsigned int*)&ws[WS_MM + (idx*32 + rep)*2 + 1],  __float_as_uint(bX));
    }

    // 3x3 is_min / death on 28x14 interior (F rows 1..14, cols 1..28)
    if (act && fy >= 1 && fy <= 14) {
        if (fx0 >= 1) {
            const float* Fc = Ft + (fy-1)*32 + (fx0-1);
            float mn = fA, mx = fA;
            #pragma unroll
            for (int dy = 0; dy < 3; dy++)
                #pragma unroll
                for (int dx = 0; dx < 3; dx++) {
                    float v = Fc[dy*32 + dx];
                    mn = fminf(mn, v); mx = fmaxf(mx, v);
                }
            if (fA <= mn) {
                int s = atomicAdd(&lcnt, 1);
                sb[s] = fA; sd[s] = mx;
            }
        }
        if (fx1 <= 28) {
            const float* Fc = Ft + (fy-1)*32 + (fx1-1);
            float mn = fB, mx = fB;
            #pragma unroll
            for (int dy = 0; dy < 3; dy++)
                #pragma unroll
                for (int dx = 0; dx < 3; dx++) {
                    float v = Fc[dy*32 + dx];
                    mn = fminf(mn, v); mx = fmaxf(mx, v);
                }
            if (fB <= mn) {
                int s = atomicAdd(&lcnt, 1);
                sb[s] = fB; sd[s] = mx;
            }
        }
    }
    __syncthreads();
    if (tid == 0)                      // 8 blocks per (image,segment) counter
        gbase = atomicAdd((int*)ws + WS_CTR + idx*SEGN + seg, lcnt);
    __syncthreads();
    int n = lcnt, gb = gbase;
    float2* list = (float2*)(ws + WS_LIST) + (size_t)idx * CAP + seg * SEGCAP;
    for (int i = tid; i < n; i += 256)
        if (gb + i < SEGCAP) list[gb + i] = make_float2(sb[i], sd[i]);
}

// Node 3: top-2 landscape per (image,t) + ticket -> last block runs the heads.
__global__ __launch_bounds__(256) void k_top2head(
        const float* __restrict__ W1, const float* __restrict__ b1,
        const float* __restrict__ W2, const float* __restrict__ b2,
        const float* __restrict__ W3, const float* __restrict__ b3,
        const float* __restrict__ fcw, const float* __restrict__ fcb,
        float* __restrict__ ws, float* __restrict__ out)
{
    __shared__ float r0s[4], r1s[4];
    __shared__ float s_tm[2];
    __shared__ int tick;
    const int tid = threadIdx.x;
    int jb = blockIdx.x;
    int idx = jb / NT, t = jb % NT;

    // reduce the 32 minmax replicas (one 32-lane shuffle tree)
    if (tid < 32) {
        unsigned mn = ((const unsigned*)ws)[WS_MM + (idx*32 + tid)*2];
        unsigned mx = ((const unsigned*)ws)[WS_MM + (idx*32 + tid)*2 + 1];
        #pragma unroll
        for (int off = 16; off; off >>= 1) {
            unsigned m2 = __shfl_down(mn, off);
            unsigned x2 = __shfl_down(mx, off);
            mn = mn > m2 ? mn : m2;
            mx = mx > x2 ? mx : x2;
        }
        if (tid == 0) { s_tm[0] = __uint_as_float(~mn); s_tm[1] = __uint_as_float(mx); }
    }
    __syncthreads();
    {
        float tmin = s_tm[0], tmax = s_tm[1];
        float tss = tmin + (tmax - tmin) * ((float)t / 24.0f);
        float a0 = 0.f, a1 = 0.f;
        for (int seg = 0; seg < SEGN; seg++) {
            int nm = ((const int*)ws)[WS_CTR + idx*SEGN + seg];
            nm = nm < SEGCAP ? nm : SEGCAP;
            const float2* list = (const float2*)(ws + WS_LIST) + (size_t)idx * CAP + seg * SEGCAP;
            for (int i = tid; i < nm; i += 256) {
                float2 p = list[i];
                float v = fmaxf(fminf(tss - p.x, p.y - tss), 0.f);
                float n0 = fmaxf(a0, v);
                a1 = fmaxf(a1, fminf(a0, v));
                a0 = n0;
            }
        }
        #pragma unroll
        for (int off = 32; off; off >>= 1) {
            float b0 = __shfl_down(a0, off);
            float b1 = __shfl_down(a1, off);
            float n0 = fmaxf(a0, b0);
            a1 = fmaxf(fminf(a0, b0), fmaxf(a1, b1));
            a0 = n0;
        }
        if ((tid & 63) == 0) { r0s[tid>>6] = a0; r1s[tid>>6] = a1; }
        __syncthreads();
        if (tid == 0) {
            float c0 = r0s[0], c1 = r1s[0];
            #pragma unroll
            for (int wv = 1; wv < 4; wv++) {
                float b0 = r0s[wv], b1 = r1s[wv];
                float n0 = fmaxf(c0, b0);
                c1 = fmaxf(fminf(c0, b0), fmaxf(c1, b1));
                c0 = n0;
            }
            // agent-scope stores: lam must be coherent across XCDs for the head block
            __hip_atomic_store(&ws[WS_LAM + (size_t)idx*50 + t*2],     c0,
                               __ATOMIC_RELAXED, __HIP_MEMORY_SCOPE_AGENT);
            __hip_atomic_store(&ws[WS_LAM + (size_t)idx*50 + t*2 + 1], c1,
                               __ATOMIC_RELAXED, __HIP_MEMORY_SCOPE_AGENT);
        }
    }
    __threadfence();                              // release
    __syncthreads();
    if (tid == 0) tick = atomicAdd((int*)ws + WS_TICK, 1);
    __syncthreads();
    if (tick != 299) return;                      // last-arriving block runs the heads
    __threadfence();                              // acquire

    __shared__ float lamS[600];
    __shared__ float xsh[600];
    for (int i = tid; i < 600; i += 256)
        lamS[i] = __hip_atomic_load(&ws[WS_LAM + i], __ATOMIC_RELAXED,
                                    __HIP_MEMORY_SCOPE_AGENT);
    __syncthreads();
    for (int j = tid; j < 600; j += 256) {
        int b = j / 150, r = j % 150, c = r / 50, o = r % 50;
        const float* Wc = (c == 0) ? W1 : (c == 1) ? W2 : W3;
        const float* bc = (c == 0) ? b1 : (c == 1) ? b2 : b3;
        const float* lam = lamS + (c*4 + b) * 50;
        float acc = bc[o];
        for (int f2 = 0; f2 < 50; f2++) acc += lam[f2] * Wc[o*50 + f2];
        xsh[j] = acc;
    }
    __syncthreads();
    if (tid < 150) {                     // signal = sum_b |x|
        float s = 0.f;
        for (int b = 0; b < 4; b++) s += fabsf(xsh[b*150 + tid]);
        out[28 + tid] = s;
    }
    if (tid < 28) {                      // output = relu(x) @ fc_w.T + fc_b
        int b = tid / 7, o = tid % 7;
        float acc = fcb[o];
        for (int j = 0; j < 150; j++) acc += fmaxf(xsh[b*150 + j], 0.f) * fcw[o*150 + j];
        out[b*7 + o] = acc;
    }
}

extern "C" void kernel_launch(void* const* d_in, const int* in_sizes, int n_in,
                              void* d_out, int out_size, void* d_ws, size_t ws_size,
                              hipStream_t stream) {
    const float* in  = (const float*)d_in[0];
    const float* W1  = (const float*)d_in[1];
    const float* b1  = (const float*)d_in[2];
    const float* W2  = (const float*)d_in[3];
    const float* b2  = (const float*)d_in[4];
    const float* W3  = (const float*)d_in[5];
    const float* b3  = (const float*)d_in[6];
    const float* fcw = (const float*)d_in[7];
    const float* fcb = (const float*)d_in[8];
    float* ws  = (float*)d_ws;
    float* out = (float*)d_out;

    k_sums    <<<NSUMJ,  256, 0, stream>>>(in, ws);
    k_dtm     <<<NTILES, 256, 0, stream>>>(in, ws);
    k_top2head<<<300,    256, 0, stream>>>(W1, b1, W2, b2, W3, b3, fcw, fcb, ws, out);
}

// Round 11
// 118.640 us; speedup vs baseline: 3.4822x; 1.0717x over previous
//
#include <hip/hip_runtime.h>
#include <math.h>

#define GH 224
#define GW 224
#define GN (GH*GW)          // 50176
#define NT 25
#define NG 20               // distinct d2 values in 11x11 window
#define CAP 24576           // per-image (birth,death) list capacity (16 segs x 1536)
#define SEGN 16
#define SEGCAP 1536
#define TILES_X 8           // 28 px wide  (8*28 = 224 exact)
#define TILES_Y 16          // 14 px tall  (16*14 = 224 exact)
#define TPI (TILES_X*TILES_Y)   // 128 tiles per image
#define NTILES (12*TPI)         // 1536
#define NSUMJ 588               // 12 images * 49 chunks of 1024 px
#define WTW 41              // w-tile stride (40 cols used; odd stride -> all 32 banks)
#define WTH 26              // (14+2)+10 tall
#define WTN (WTW*WTH)       // 1066
#define SW 30               // S1/S2 cols (F cols -1..28)
#define SH 26               // S1/S2 rows (w rows of tile)

// ws float offsets:
// [16..784)    minmax replicas: per image 32 x (mn_invbits, mx_bits), uint atomicMax
// [784..976)   per-(image,segment) minima counters (12*16 ints)
// [976]        ticket (int)
// [1024..1624) lam[12][50]
// [1664..2252) 588 per-chunk sum partials
// [4096..)     per-image lists: float2[CAP], segmented 16 x 1536
#define WS_MM   16
#define WS_CTR  784
#define WS_TICK 976
#define WS_LAM  1024
#define WS_SUMP 1664
#define WS_LIST 4096

// Group table (exact fallback path only): group id per (dy,dx) = rank of its d2
// among the 20 distinct values ascending == stable-argsort run partition
// (HW-verified R4..R10: clip-fill over an equal-d2 run == one clip of run sum).
struct GrpTbl { int g[11][11]; float gd2[NG]; };
constexpr GrpTbl make_g() {
    GrpTbl t{};
    int n = 0;
    for (int v = 0; v <= 50; v++) {
        bool found = false;
        for (int dy = -5; dy <= 5 && !found; dy++)
            for (int dx = -5; dx <= 5 && !found; dx++)
                if (dy*dy + dx*dx == v) found = true;
        if (found) { t.gd2[n] = (float)v; n++; }
    }
    for (int dy = 0; dy < 11; dy++)
        for (int dx = 0; dx < 11; dx++) {
            int d2 = (dy-5)*(dy-5) + (dx-5)*(dx-5);
            for (int k = 0; k < NG; k++)
                if ((float)d2 == t.gd2[k]) t.g[dy][dx] = k;
        }
    return t;
}
constexpr GrpTbl TG = make_g();
__device__ __constant__ float KD2[11] = {25.f,16.f,9.f,4.f,1.f,0.f,1.f,4.f,9.f,16.f,25.f};

// Node 1: zero ctl region [0..1024) (disjoint float4 per block) + sum partials.
__global__ __launch_bounds__(256) void k_sums(const float* __restrict__ in, float* __restrict__ ws) {
    __shared__ float sh4[4];
    int j = blockIdx.x;
    if (j < 256 && threadIdx.x == 0)
        ((float4*)ws)[j] = make_float4(0.f, 0.f, 0.f, 0.f);
    int idx = j / 49, chunk = j % 49;
    int cc = idx >> 2, bb = idx & 3;
    const float4* w4 = (const float4*)(in + (size_t)(bb*3 + cc) * GN);
    float4 v = w4[chunk*256 + threadIdx.x];
    float s = v.x + v.y + v.z + v.w;
    #pragma unroll
    for (int off = 32; off; off >>= 1) s += __shfl_down(s, off);
    if ((threadIdx.x & 63) == 0) sh4[threadIdx.x >> 6] = s;
    __syncthreads();
    if (threadIdx.x == 0) ws[WS_SUMP + j] = sh4[0] + sh4[1] + sh4[2] + sh4[3];
}

// Node 2: DTM via SEPARABLE convolution (clip never binds: bound ~1254 >> window
// sum ~60; checked per point, exact grouped fallback if ever violated) + 3x3
// min/max + minima compaction per 28x14 tile. De-contended atomics (R10).
__global__ __launch_bounds__(256) void k_dtm(const float* __restrict__ in, float* __restrict__ ws) {
    __shared__ float wt[WTN];
    __shared__ float S1[SH*SW], S2[SH*SW];
    __shared__ float Ft[16*32];        // 16 rows x stride 32 (cols 0..29 valid)
    __shared__ float sb[416], sd[416];
    __shared__ float smn[4], smx[4];
    __shared__ float sbound;
    __shared__ int lcnt, gbase;
    const int tid = threadIdx.x;

    int tile_id = blockIdx.x;
    int idx  = tile_id / TPI;
    int trem = tile_id % TPI;
    int tyi = trem / TILES_X, txi = trem % TILES_X;
    int gy = tyi*14, gx = txi*28;      // interior origin
    int cc = idx >> 2, bb = idx & 3;
    const float* w = in + (size_t)(bb*3 + cc) * GN;
    int rep = trem & 31;               // minmax replica
    int seg = trem & 15;               // list segment

    // bound = 0.05 * sum(image) from 49 partials (fixed-order -> identical per image)
    if (tid < 64) {
        float p = (tid < 49) ? ws[WS_SUMP + idx*49 + tid] : 0.f;
        #pragma unroll
        for (int off = 32; off; off >>= 1) p += __shfl_down(p, off);
        if (tid == 0) { sbound = 0.05f * p; lcnt = 0; }
    }

    // stage border-clamped w halo tile 26 x (40 used / 41 stride)
    int wy0 = gy - 6, wx0 = gx - 6;
    for (int i = tid; i < WTN; i += 256) {
        int r = i / WTW, q = i % WTW;
        int yy = wy0 + r; yy = yy < 0 ? 0 : (yy > GH-1 ? GH-1 : yy);
        int xx = wx0 + q; xx = xx < 0 ? 0 : (xx > GW-1 ? GW-1 : xx);
        wt[i] = w[yy*GW + xx];
    }
    __syncthreads();

    // horizontal pass: S1 = box sum, S2 = dx^2-weighted sum, per (w-row, F-col)
    for (int e = tid; e < SH*SW; e += 256) {
        int r = e / SW, fc = e % SW;
        int pxc = gx - 1 + fc; pxc = pxc < 0 ? 0 : (pxc > GW-1 ? GW-1 : pxc);
        const float* bp = wt + r*WTW + (pxc - wx0 - 5);
        float s1 = 0.f, s2 = 0.f;
        #pragma unroll
        for (int k = 0; k < 11; k++) {
            float v = bp[k];
            s1 += v;
            s2 = fmaf(KD2[k], v, s2);
        }
        S1[e] = s1; S2[e] = s2;
    }
    __syncthreads();

    // vertical pass: two F-points per thread (rows fy0, fy0+8), col fc
    const bool act = tid < 240;        // 8 row-starts x 30 cols
    int fy0 = act ? tid / 30 : 0;
    int fc  = act ? tid % 30 : 0;
    float bound = sbound;
    float fv[2] = {0.f, 0.f};
    if (act) {
        int pxc = gx - 1 + fc; pxc = pxc < 0 ? 0 : (pxc > GW-1 ? GW-1 : pxc);
        int cb = pxc - wx0 - 5;
        #pragma unroll
        for (int h = 0; h < 2; h++) {
            int fy = fy0 + h*8;
            int py = gy - 1 + fy; int pyc = py < 0 ? 0 : (py > GH-1 ? GH-1 : py);
            int vb = pyc - wy0 - 5;
            float a = 0.f, b2 = 0.f, cumT = 0.f;
            #pragma unroll
            for (int k = 0; k < 11; k++) {
                float s1 = S1[(vb+k)*SW + fc];
                float s2 = S2[(vb+k)*SW + fc];
                a = fmaf(KD2[k], s1, a);
                b2 += s2;
                cumT += s1;
            }
            float acc = a + b2;
            if (bound < cumT) {        // exact grouped path (never for bench input)
                const float* basep = wt + vb*WTW + cb;
                float cum = 0.f; acc = 0.f;
                for (int g = 0; g < NG; g++) {
                    float gs = 0.f;
                    for (int r = 0; r < 11; r++)
                        for (int c = 0; c < 11; c++)
                            if (TG.g[r][c] == g) gs += basep[r*WTW + c];
                    float v = bound - cum;
                    v = v < 0.f ? 0.f : v;
                    v = v > gs ? gs : v;
                    acc = fmaf(v, TG.gd2[g], acc);
                    cum += gs;
                }
            }
            fv[h] = sqrtf(acc / bound + 1e-12f);
            Ft[fy*32 + fc] = fv[h];
        }
    }
    float mnv = INFINITY, mxv = -INFINITY;
    if (act) { mnv = fminf(fv[0], fv[1]); mxv = fmaxf(fv[0], fv[1]); }  // halo = clamped dups, safe
    #pragma unroll
    for (int off = 32; off; off >>= 1) {
        mnv = fminf(mnv, __shfl_down(mnv, off));
        mxv = fmaxf(mxv, __shfl_down(mxv, off));
    }
    if ((tid & 63) == 0) { smn[tid>>6] = mnv; smx[tid>>6] = mxv; }
    __syncthreads();                   // Ft complete + smn/smx ready
    if (tid == 0) {
        float bm = fminf(fminf(smn[0], smn[1]), fminf(smn[2], smn[3]));
        float bX = fmaxf(fmaxf(smx[0], smx[1]), fmaxf(smx[2], smx[3]));
        atomicMax((unsigned int*)&ws[WS_MM + (idx*32 + rep)*2],     ~__float_as_uint(bm));
        atomicMax((unsigned int*)&ws[WS_MM + (idx*32 + rep)*2 + 1],  __float_as_uint(bX));
    }

    // 3x3 is_min / death on 28x14 interior (F rows 1..14, cols 1..28)
    if (act && fc >= 1 && fc <= 28) {
        #pragma unroll
        for (int h = 0; h < 2; h++) {
            int fy = fy0 + h*8;
            if (fy >= 1 && fy <= 14) {
                const float* Fc = Ft + (fy-1)*32 + (fc-1);
                float f = fv[h];
                float mn = f, mx = f;
                #pragma unroll
                for (int dy = 0; dy < 3; dy++)
                    #pragma unroll
                    for (int dx = 0; dx < 3; dx++) {
                        float v = Fc[dy*32 + dx];
                        mn = fminf(mn, v); mx = fmaxf(mx, v);
                    }
                if (f <= mn) {
                    int s = atomicAdd(&lcnt, 1);
                    sb[s] = f; sd[s] = mx;
                }
            }
        }
    }
    __syncthreads();
    if (tid == 0)                      // 8 blocks per (image,segment) counter
        gbase = atomicAdd((int*)ws + WS_CTR + idx*SEGN + seg, lcnt);
    __syncthreads();
    int n = lcnt, gb = gbase;
    float2* list = (float2*)(ws + WS_LIST) + (size_t)idx * CAP + seg * SEGCAP;
    for (int i = tid; i < n; i += 256)
        if (gb + i < SEGCAP) list[gb + i] = make_float2(sb[i], sd[i]);
}

// Node 3: top-2 landscape per (image,t) + ticket -> last block runs the heads.
__global__ __launch_bounds__(256) void k_top2head(
        const float* __restrict__ W1, const float* __restrict__ b1,
        const float* __restrict__ W2, const float* __restrict__ b2,
        const float* __restrict__ W3, const float* __restrict__ b3,
        const float* __restrict__ fcw, const float* __restrict__ fcb,
        float* __restrict__ ws, float* __restrict__ out)
{
    __shared__ float r0s[4], r1s[4];
    __shared__ float s_tm[2];
    __shared__ int tick;
    const int tid = threadIdx.x;
    int jb = blockIdx.x;
    int idx = jb / NT, t = jb % NT;

    // reduce the 32 minmax replicas (one 32-lane shuffle tree)
    if (tid < 32) {
        unsigned mn = ((const unsigned*)ws)[WS_MM + (idx*32 + tid)*2];
        unsigned mx = ((const unsigned*)ws)[WS_MM + (idx*32 + tid)*2 + 1];
        #pragma unroll
        for (int off = 16; off; off >>= 1) {
            unsigned m2 = __shfl_down(mn, off);
            unsigned x2 = __shfl_down(mx, off);
            mn = mn > m2 ? mn : m2;
            mx = mx > x2 ? mx : x2;
        }
        if (tid == 0) { s_tm[0] = __uint_as_float(~mn); s_tm[1] = __uint_as_float(mx); }
    }
    __syncthreads();
    {
        float tmin = s_tm[0], tmax = s_tm[1];
        float tss = tmin + (tmax - tmin) * ((float)t / 24.0f);
        float a0 = 0.f, a1 = 0.f;
        for (int seg = 0; seg < SEGN; seg++) {
            int nm = ((const int*)ws)[WS_CTR + idx*SEGN + seg];
            nm = nm < SEGCAP ? nm : SEGCAP;
            const float2* list = (const float2*)(ws + WS_LIST) + (size_t)idx * CAP + seg * SEGCAP;
            for (int i = tid; i < nm; i += 256) {
                float2 p = list[i];
                float v = fmaxf(fminf(tss - p.x, p.y - tss), 0.f);
                float n0 = fmaxf(a0, v);
                a1 = fmaxf(a1, fminf(a0, v));
                a0 = n0;
            }
        }
        #pragma unroll
        for (int off = 32; off; off >>= 1) {
            float b0 = __shfl_down(a0, off);
            float b1 = __shfl_down(a1, off);
            float n0 = fmaxf(a0, b0);
            a1 = fmaxf(fminf(a0, b0), fmaxf(a1, b1));
            a0 = n0;
        }
        if ((tid & 63) == 0) { r0s[tid>>6] = a0; r1s[tid>>6] = a1; }
        __syncthreads();
        if (tid == 0) {
            float c0 = r0s[0], c1 = r1s[0];
            #pragma unroll
            for (int wv = 1; wv < 4; wv++) {
                float b0 = r0s[wv], b1 = r1s[wv];
                float n0 = fmaxf(c0, b0);
                c1 = fmaxf(fminf(c0, b0), fmaxf(c1, b1));
                c0 = n0;
            }
            __hip_atomic_store(&ws[WS_LAM + (size_t)idx*50 + t*2],     c0,
                               __ATOMIC_RELAXED, __HIP_MEMORY_SCOPE_AGENT);
            __hip_atomic_store(&ws[WS_LAM + (size_t)idx*50 + t*2 + 1], c1,
                               __ATOMIC_RELAXED, __HIP_MEMORY_SCOPE_AGENT);
        }
    }
    __threadfence();                              // release
    __syncthreads();
    if (tid == 0) tick = atomicAdd((int*)ws + WS_TICK, 1);
    __syncthreads();
    if (tick != 299) return;                      // last-arriving block runs the heads
    __threadfence();                              // acquire

    __shared__ float lamS[600];
    __shared__ float xsh[600];
    for (int i = tid; i < 600; i += 256)
        lamS[i] = __hip_atomic_load(&ws[WS_LAM + i], __ATOMIC_RELAXED,
                                    __HIP_MEMORY_SCOPE_AGENT);
    __syncthreads();
    for (int j = tid; j < 600; j += 256) {
        int b = j / 150, r = j % 150, c = r / 50, o = r % 50;
        const float* Wc = (c == 0) ? W1 : (c == 1) ? W2 : W3;
        const float* bc = (c == 0) ? b1 : (c == 1) ? b2 : b3;
        const float* lam = lamS + (c*4 + b) * 50;
        float acc = bc[o];
        for (int f2 = 0; f2 < 50; f2++) acc += lam[f2] * Wc[o*50 + f2];
        xsh[j] = acc;
    }
    __syncthreads();
    if (tid < 150) {                     // signal = sum_b |x|
        float s = 0.f;
        for (int b = 0; b < 4; b++) s += fabsf(xsh[b*150 + tid]);
        out[28 + tid] = s;
    }
    if (tid < 28) {                      // output = relu(x) @ fc_w.T + fc_b
        int b = tid / 7, o = tid % 7;
        float acc = fcb[o];
        for (int j = 0; j < 150; j++) acc += fmaxf(xsh[b*150 + j], 0.f) * fcw[o*150 + j];
        out[b*7 + o] = acc;
    }
}

extern "C" void kernel_launch(void* const* d_in, const int* in_sizes, int n_in,
                              void* d_out, int out_size, void* d_ws, size_t ws_size,
                              hipStream_t stream) {
    const float* in  = (const float*)d_in[0];
    const float* W1  = (const float*)d_in[1];
    const float* b1  = (const float*)d_in[2];
    const float* W2  = (const float*)d_in[3];
    const float* b2  = (const float*)d_in[4];
    const float* W3  = (const float*)d_in[5];
    const float* b3  = (const float*)d_in[6];
    const float* fcw = (const float*)d_in[7];
    const float* fcb = (const float*)d_in[8];
    float* ws  = (float*)d_ws;
    float* out = (float*)d_out;

    k_sums    <<<NSUMJ,  256, 0, stream>>>(in, ws);
    k_dtm     <<<NTILES, 256, 0, stream>>>(in, ws);
    k_top2head<<<300,    256, 0, stream>>>(W1, b1, W2, b2, W3, b3, fcw, fcb, ws, out);
}

// Round 12
// 118.119 us; speedup vs baseline: 3.4976x; 1.0044x over previous
//
#include <hip/hip_runtime.h>
#include <math.h>

#define GH 224
#define GW 224
#define GN (GH*GW)          // 50176
#define NT 25
#define NG 20               // distinct d2 values in 11x11 window
#define CAP 24576           // per-image (birth,death) list capacity (16 segs x 1536)
#define SEGN 16
#define SEGCAP 1536
#define TILES_X 8           // 28 px wide  (8*28 = 224 exact)
#define TILES_Y 16          // 14 px tall  (16*14 = 224 exact)
#define TPI (TILES_X*TILES_Y)   // 128 tiles per image
#define NTILES (12*TPI)         // 1536
#define NSUMJ 588               // 12 images * 49 chunks of 1024 px
#define WTW 40              // w-tile stride (row-major stride-1 access -> conflict-free)
#define WTH 26              // (14+2)+10 tall
#define WTN (WTW*WTH)       // 1040
#define SW 30               // S1/S2 cols (F cols -1..28)
#define SH 26               // S1/S2 rows (w rows of tile)

// ws float offsets:
// [16..784)    minmax replicas: per image 32 x (mn_invbits, mx_bits), uint atomicMax
// [784..976)   per-(image,segment) minima counters (12*16 ints)
// [976]        ticket (int)
// [1024..1624) lam[12][50]
// [1664..2252) 588 per-chunk sum partials
// [4096..)     per-image lists: float2[CAP], segmented 16 x 1536
#define WS_MM   16
#define WS_CTR  784
#define WS_TICK 976
#define WS_LAM  1024
#define WS_SUMP 1664
#define WS_LIST 4096

// Group table (exact fallback path only): group id per (dy,dx) = rank of its d2
// among the 20 distinct values ascending == stable-argsort run partition
// (HW-verified R4..R11: clip-fill over an equal-d2 run == one clip of run sum).
struct GrpTbl { int g[11][11]; float gd2[NG]; };
constexpr GrpTbl make_g() {
    GrpTbl t{};
    int n = 0;
    for (int v = 0; v <= 50; v++) {
        bool found = false;
        for (int dy = -5; dy <= 5 && !found; dy++)
            for (int dx = -5; dx <= 5 && !found; dx++)
                if (dy*dy + dx*dx == v) found = true;
        if (found) { t.gd2[n] = (float)v; n++; }
    }
    for (int dy = 0; dy < 11; dy++)
        for (int dx = 0; dx < 11; dx++) {
            int d2 = (dy-5)*(dy-5) + (dx-5)*(dx-5);
            for (int k = 0; k < NG; k++)
                if ((float)d2 == t.gd2[k]) t.g[dy][dx] = k;
        }
    return t;
}
constexpr GrpTbl TG = make_g();
__device__ __constant__ float KD2[11] = {25.f,16.f,9.f,4.f,1.f,0.f,1.f,4.f,9.f,16.f,25.f};

// Node 1: zero ctl region [0..1024) (disjoint float4 per block) + sum partials.
__global__ __launch_bounds__(256) void k_sums(const float* __restrict__ in, float* __restrict__ ws) {
    __shared__ float sh4[4];
    int j = blockIdx.x;
    if (j < 256 && threadIdx.x == 0)
        ((float4*)ws)[j] = make_float4(0.f, 0.f, 0.f, 0.f);
    int idx = j / 49, chunk = j % 49;
    int cc = idx >> 2, bb = idx & 3;
    const float4* w4 = (const float4*)(in + (size_t)(bb*3 + cc) * GN);
    float4 v = w4[chunk*256 + threadIdx.x];
    float s = v.x + v.y + v.z + v.w;
    #pragma unroll
    for (int off = 32; off; off >>= 1) s += __shfl_down(s, off);
    if ((threadIdx.x & 63) == 0) sh4[threadIdx.x >> 6] = s;
    __syncthreads();
    if (threadIdx.x == 0) ws[WS_SUMP + j] = sh4[0] + sh4[1] + sh4[2] + sh4[3];
}

// Node 2: DTM via separable convolution (clip never binds; per-point check with
// exact grouped fallback) + 3x3 min/max + minima compaction per 28x14 tile.
// R12: float2-vectorized staging for x-interior tiles (wx0 = 28*txi - 6 is even
// -> aligned; y-clamp preserves row contiguity). Values/order bit-identical.
__global__ __launch_bounds__(256) void k_dtm(const float* __restrict__ in, float* __restrict__ ws) {
    __shared__ float wt[WTN];
    __shared__ float S1[SH*SW], S2[SH*SW];
    __shared__ float Ft[16*32];        // 16 rows x stride 32 (cols 0..29 valid)
    __shared__ float sb[416], sd[416];
    __shared__ float smn[4], smx[4];
    __shared__ float sbound;
    __shared__ int lcnt, gbase;
    const int tid = threadIdx.x;

    int tile_id = blockIdx.x;
    int idx  = tile_id / TPI;
    int trem = tile_id % TPI;
    int tyi = trem / TILES_X, txi = trem % TILES_X;
    int gy = tyi*14, gx = txi*28;      // interior origin
    int cc = idx >> 2, bb = idx & 3;
    const float* w = in + (size_t)(bb*3 + cc) * GN;
    int rep = trem & 31;               // minmax replica
    int seg = trem & 15;               // list segment

    // bound = 0.05 * sum(image) from 49 partials (fixed-order -> identical per image)
    if (tid < 64) {
        float p = (tid < 49) ? ws[WS_SUMP + idx*49 + tid] : 0.f;
        #pragma unroll
        for (int off = 32; off; off >>= 1) p += __shfl_down(p, off);
        if (tid == 0) { sbound = 0.05f * p; lcnt = 0; }
    }

    // stage border-clamped w halo tile 26 x 40
    int wy0 = gy - 6, wx0 = gx - 6;
    if (txi != 0 && txi != TILES_X-1) {
        // x-interior: rows contiguous in global (only y clamps); float2, aligned
        for (int i = tid; i < SH*20; i += 256) {
            int r = i / 20, q = i % 20;
            int yy = wy0 + r; yy = yy < 0 ? 0 : (yy > GH-1 ? GH-1 : yy);
            ((float2*)wt)[r*20 + q] = ((const float2*)(w + yy*GW + wx0))[q];
        }
    } else {
        for (int i = tid; i < WTN; i += 256) {
            int r = i / WTW, q = i % WTW;
            int yy = wy0 + r; yy = yy < 0 ? 0 : (yy > GH-1 ? GH-1 : yy);
            int xx = wx0 + q; xx = xx < 0 ? 0 : (xx > GW-1 ? GW-1 : xx);
            wt[i] = w[yy*GW + xx];
        }
    }
    __syncthreads();

    // horizontal pass: S1 = box sum, S2 = dx^2-weighted sum, per (w-row, F-col)
    for (int e = tid; e < SH*SW; e += 256) {
        int r = e / SW, fc = e % SW;
        int pxc = gx - 1 + fc; pxc = pxc < 0 ? 0 : (pxc > GW-1 ? GW-1 : pxc);
        const float* bp = wt + r*WTW + (pxc - wx0 - 5);
        float s1 = 0.f, s2 = 0.f;
        #pragma unroll
        for (int k = 0; k < 11; k++) {
            float v = bp[k];
            s1 += v;
            s2 = fmaf(KD2[k], v, s2);
        }
        S1[e] = s1; S2[e] = s2;
    }
    __syncthreads();

    // vertical pass: two F-points per thread (rows fy0, fy0+8), col fc
    const bool act = tid < 240;        // 8 row-starts x 30 cols
    int fy0 = act ? tid / 30 : 0;
    int fc  = act ? tid % 30 : 0;
    float bound = sbound;
    float fv[2] = {0.f, 0.f};
    if (act) {
        int pxc = gx - 1 + fc; pxc = pxc < 0 ? 0 : (pxc > GW-1 ? GW-1 : pxc);
        int cb = pxc - wx0 - 5;
        #pragma unroll
        for (int h = 0; h < 2; h++) {
            int fy = fy0 + h*8;
            int py = gy - 1 + fy; int pyc = py < 0 ? 0 : (py > GH-1 ? GH-1 : py);
            int vb = pyc - wy0 - 5;
            float a = 0.f, b2 = 0.f, cumT = 0.f;
            #pragma unroll
            for (int k = 0; k < 11; k++) {
                float s1 = S1[(vb+k)*SW + fc];
                float s2 = S2[(vb+k)*SW + fc];
                a = fmaf(KD2[k], s1, a);
                b2 += s2;
                cumT += s1;
            }
            float acc = a + b2;
            if (bound < cumT) {        // exact grouped path (never for bench input)
                const float* basep = wt + vb*WTW + cb;
                float cum = 0.f; acc = 0.f;
                for (int g = 0; g < NG; g++) {
                    float gs = 0.f;
                    for (int r = 0; r < 11; r++)
                        for (int c = 0; c < 11; c++)
                            if (TG.g[r][c] == g) gs += basep[r*WTW + c];
                    float v = bound - cum;
                    v = v < 0.f ? 0.f : v;
                    v = v > gs ? gs : v;
                    acc = fmaf(v, TG.gd2[g], acc);
                    cum += gs;
                }
            }
            fv[h] = sqrtf(acc / bound + 1e-12f);
            Ft[fy*32 + fc] = fv[h];
        }
    }
    float mnv = INFINITY, mxv = -INFINITY;
    if (act) { mnv = fminf(fv[0], fv[1]); mxv = fmaxf(fv[0], fv[1]); }  // halo = clamped dups, safe
    #pragma unroll
    for (int off = 32; off; off >>= 1) {
        mnv = fminf(mnv, __shfl_down(mnv, off));
        mxv = fmaxf(mxv, __shfl_down(mxv, off));
    }
    if ((tid & 63) == 0) { smn[tid>>6] = mnv; smx[tid>>6] = mxv; }
    __syncthreads();                   // Ft complete + smn/smx ready
    if (tid == 0) {
        float bm = fminf(fminf(smn[0], smn[1]), fminf(smn[2], smn[3]));
        float bX = fmaxf(fmaxf(smx[0], smx[1]), fmaxf(smx[2], smx[3]));
        atomicMax((unsigned int*)&ws[WS_MM + (idx*32 + rep)*2],     ~__float_as_uint(bm));
        atomicMax((unsigned int*)&ws[WS_MM + (idx*32 + rep)*2 + 1],  __float_as_uint(bX));
    }

    // 3x3 is_min / death on 28x14 interior (F rows 1..14, cols 1..28)
    if (act && fc >= 1 && fc <= 28) {
        #pragma unroll
        for (int h = 0; h < 2; h++) {
            int fy = fy0 + h*8;
            if (fy >= 1 && fy <= 14) {
                const float* Fc = Ft + (fy-1)*32 + (fc-1);
                float f = fv[h];
                float mn = f, mx = f;
                #pragma unroll
                for (int dy = 0; dy < 3; dy++)
                    #pragma unroll
                    for (int dx = 0; dx < 3; dx++) {
                        float v = Fc[dy*32 + dx];
                        mn = fminf(mn, v); mx = fmaxf(mx, v);
                    }
                if (f <= mn) {
                    int s = atomicAdd(&lcnt, 1);
                    sb[s] = f; sd[s] = mx;
                }
            }
        }
    }
    __syncthreads();
    if (tid == 0)                      // 8 blocks per (image,segment) counter
        gbase = atomicAdd((int*)ws + WS_CTR + idx*SEGN + seg, lcnt);
    __syncthreads();
    int n = lcnt, gb = gbase;
    float2* list = (float2*)(ws + WS_LIST) + (size_t)idx * CAP + seg * SEGCAP;
    for (int i = tid; i < n; i += 256)
        if (gb + i < SEGCAP) list[gb + i] = make_float2(sb[i], sd[i]);
}

// Node 3: top-2 landscape per (image,t) + ticket -> last block runs the heads.
__global__ __launch_bounds__(256) void k_top2head(
        const float* __restrict__ W1, const float* __restrict__ b1,
        const float* __restrict__ W2, const float* __restrict__ b2,
        const float* __restrict__ W3, const float* __restrict__ b3,
        const float* __restrict__ fcw, const float* __restrict__ fcb,
        float* __restrict__ ws, float* __restrict__ out)
{
    __shared__ float r0s[4], r1s[4];
    __shared__ float s_tm[2];
    __shared__ int tick;
    const int tid = threadIdx.x;
    int jb = blockIdx.x;
    int idx = jb / NT, t = jb % NT;

    // reduce the 32 minmax replicas (one 32-lane shuffle tree)
    if (tid < 32) {
        unsigned mn = ((const unsigned*)ws)[WS_MM + (idx*32 + tid)*2];
        unsigned mx = ((const unsigned*)ws)[WS_MM + (idx*32 + tid)*2 + 1];
        #pragma unroll
        for (int off = 16; off; off >>= 1) {
            unsigned m2 = __shfl_down(mn, off);
            unsigned x2 = __shfl_down(mx, off);
            mn = mn > m2 ? mn : m2;
            mx = mx > x2 ? mx : x2;
        }
        if (tid == 0) { s_tm[0] = __uint_as_float(~mn); s_tm[1] = __uint_as_float(mx); }
    }
    __syncthreads();
    {
        float tmin = s_tm[0], tmax = s_tm[1];
        float tss = tmin + (tmax - tmin) * ((float)t / 24.0f);
        float a0 = 0.f, a1 = 0.f;
        for (int seg = 0; seg < SEGN; seg++) {
            int nm = ((const int*)ws)[WS_CTR + idx*SEGN + seg];
            nm = nm < SEGCAP ? nm : SEGCAP;
            const float2* list = (const float2*)(ws + WS_LIST) + (size_t)idx * CAP + seg * SEGCAP;
            for (int i = tid; i < nm; i += 256) {
                float2 p = list[i];
                float v = fmaxf(fminf(tss - p.x, p.y - tss), 0.f);
                float n0 = fmaxf(a0, v);
                a1 = fmaxf(a1, fminf(a0, v));
                a0 = n0;
            }
        }
        #pragma unroll
        for (int off = 32; off; off >>= 1) {
            float b0 = __shfl_down(a0, off);
            float b1 = __shfl_down(a1, off);
            float n0 = fmaxf(a0, b0);
            a1 = fmaxf(fminf(a0, b0), fmaxf(a1, b1));
            a0 = n0;
        }
        if ((tid & 63) == 0) { r0s[tid>>6] = a0; r1s[tid>>6] = a1; }
        __syncthreads();
        if (tid == 0) {
            float c0 = r0s[0], c1 = r1s[0];
            #pragma unroll
            for (int wv = 1; wv < 4; wv++) {
                float b0 = r0s[wv], b1 = r1s[wv];
                float n0 = fmaxf(c0, b0);
                c1 = fmaxf(fminf(c0, b0), fmaxf(c1, b1));
                c0 = n0;
            }
            __hip_atomic_store(&ws[WS_LAM + (size_t)idx*50 + t*2],     c0,
                               __ATOMIC_RELAXED, __HIP_MEMORY_SCOPE_AGENT);
            __hip_atomic_store(&ws[WS_LAM + (size_t)idx*50 + t*2 + 1], c1,
                               __ATOMIC_RELAXED, __HIP_MEMORY_SCOPE_AGENT);
        }
    }
    __threadfence();                              // release
    __syncthreads();
    if (tid == 0) tick = atomicAdd((int*)ws + WS_TICK, 1);
    __syncthreads();
    if (tick != 299) return;                      // last-arriving block runs the heads
    __threadfence();                              // acquire

    __shared__ float lamS[600];
    __shared__ float xsh[600];
    for (int i = tid; i < 600; i += 256)
        lamS[i] = __hip_atomic_load(&ws[WS_LAM + i], __ATOMIC_RELAXED,
                                    __HIP_MEMORY_SCOPE_AGENT);
    __syncthreads();
    for (int j = tid; j < 600; j += 256) {
        int b = j / 150, r = j % 150, c = r / 50, o = r % 50;
        const float* Wc = (c == 0) ? W1 : (c == 1) ? W2 : W3;
        const float* bc = (c == 0) ? b1 : (c == 1) ? b2 : b3;
        const float* lam = lamS + (c*4 + b) * 50;
        float acc = bc[o];
        for (int f2 = 0; f2 < 50; f2++) acc += lam[f2] * Wc[o*50 + f2];
        xsh[j] = acc;
    }
    __syncthreads();
    if (tid < 150) {                     // signal = sum_b |x|
        float s = 0.f;
        for (int b = 0; b < 4; b++) s += fabsf(xsh[b*150 + tid]);
        out[28 + tid] = s;
    }
    if (tid < 28) {                      // output = relu(x) @ fc_w.T + fc_b
        int b = tid / 7, o = tid % 7;
        float acc = fcb[o];
        for (int j = 0; j < 150; j++) acc += fmaxf(xsh[b*150 + j], 0.f) * fcw[o*150 + j];
        out[b*7 + o] = acc;
    }
}

extern "C" void kernel_launch(void* const* d_in, const int* in_sizes, int n_in,
                              void* d_out, int out_size, void* d_ws, size_t ws_size,
                              hipStream_t stream) {
    const float* in  = (const float*)d_in[0];
    const float* W1  = (const float*)d_in[1];
    const float* b1  = (const float*)d_in[2];
    const float* W2  = (const float*)d_in[3];
    const float* b2  = (const float*)d_in[4];
    const float* W3  = (const float*)d_in[5];
    const float* b3  = (const float*)d_in[6];
    const float* fcw = (const float*)d_in[7];
    const float* fcb = (const float*)d_in[8];
    float* ws  = (float*)d_ws;
    float* out = (float*)d_out;

    k_sums    <<<NSUMJ,  256, 0, stream>>>(in, ws);
    k_dtm     <<<NTILES, 256, 0, stream>>>(in, ws);
    k_top2head<<<300,    256, 0, stream>>>(W1, b1, W2, b2, W3, b3, fcw, fcb, ws, out);
}

// Round 13
// 102.352 us; speedup vs baseline: 4.0363x; 1.1540x over previous
//
#include <hip/hip_runtime.h>
#include <math.h>

#define GH 224
#define GW 224
#define GN (GH*GW)          // 50176
#define NT 25
#define NG 20               // distinct d2 values in 11x11 window
#define CAP 24576           // per-image (birth,death) list capacity (16 segs x 1536)
#define SEGN 16
#define SEGCAP 1536
#define TILES_X 8           // 28 px wide  (8*28 = 224 exact)
#define TILES_Y 16          // 14 px tall  (16*14 = 224 exact)
#define TPI (TILES_X*TILES_Y)   // 128 tiles per image
#define NTILES (12*TPI)         // 1536
#define NSUMJ 588               // 12 images * 49 chunks of 1024 px
#define WTW 40              // w-tile stride (row-major stride-1 access -> conflict-free)
#define WTH 26              // (14+2)+10 tall
#define WTN (WTW*WTH)       // 1040
#define SW 30               // S1/S2 cols (F cols -1..28)
#define SH 26               // S1/S2 rows (w rows of tile)

// ws float offsets:
// [16..784)    minmax replicas: per image 32 x (mn_invbits, mx_bits), uint atomicMax
// [784..976)   per-(image,segment) minima counters (12*16 ints)
// [1024..1624) lam[12][50]
// [1664..2252) 588 per-chunk sum partials
// [4096..)     per-image lists: float2[CAP], segmented 16 x 1536
#define WS_MM   16
#define WS_CTR  784
#define WS_LAM  1024
#define WS_SUMP 1664
#define WS_LIST 4096

// Group table (exact fallback path only): group id per (dy,dx) = rank of its d2
// among the 20 distinct values ascending == stable-argsort run partition
// (HW-verified R4..R12: clip-fill over an equal-d2 run == one clip of run sum).
struct GrpTbl { int g[11][11]; float gd2[NG]; };
constexpr GrpTbl make_g() {
    GrpTbl t{};
    int n = 0;
    for (int v = 0; v <= 50; v++) {
        bool found = false;
        for (int dy = -5; dy <= 5 && !found; dy++)
            for (int dx = -5; dx <= 5 && !found; dx++)
                if (dy*dy + dx*dx == v) found = true;
        if (found) { t.gd2[n] = (float)v; n++; }
    }
    for (int dy = 0; dy < 11; dy++)
        for (int dx = 0; dx < 11; dx++) {
            int d2 = (dy-5)*(dy-5) + (dx-5)*(dx-5);
            for (int k = 0; k < NG; k++)
                if ((float)d2 == t.gd2[k]) t.g[dy][dx] = k;
        }
    return t;
}
constexpr GrpTbl TG = make_g();
__device__ __constant__ float KD2[11] = {25.f,16.f,9.f,4.f,1.f,0.f,1.f,4.f,9.f,16.f,25.f};

// Node 1: zero ctl region [0..1024) (disjoint float4 per block) + sum partials.
__global__ __launch_bounds__(256) void k_sums(const float* __restrict__ in, float* __restrict__ ws) {
    __shared__ float sh4[4];
    int j = blockIdx.x;
    if (j < 256 && threadIdx.x == 0)
        ((float4*)ws)[j] = make_float4(0.f, 0.f, 0.f, 0.f);
    int idx = j / 49, chunk = j % 49;
    int cc = idx >> 2, bb = idx & 3;
    const float4* w4 = (const float4*)(in + (size_t)(bb*3 + cc) * GN);
    float4 v = w4[chunk*256 + threadIdx.x];
    float s = v.x + v.y + v.z + v.w;
    #pragma unroll
    for (int off = 32; off; off >>= 1) s += __shfl_down(s, off);
    if ((threadIdx.x & 63) == 0) sh4[threadIdx.x >> 6] = s;
    __syncthreads();
    if (threadIdx.x == 0) ws[WS_SUMP + j] = sh4[0] + sh4[1] + sh4[2] + sh4[3];
}

// Node 2: DTM via separable convolution (clip never binds; per-point check with
// exact grouped fallback) + 3x3 min/max + minima compaction per 28x14 tile.
__global__ __launch_bounds__(256) void k_dtm(const float* __restrict__ in, float* __restrict__ ws) {
    __shared__ float wt[WTN];
    __shared__ float S1[SH*SW], S2[SH*SW];
    __shared__ float Ft[16*32];        // 16 rows x stride 32 (cols 0..29 valid)
    __shared__ float sb[416], sd[416];
    __shared__ float smn[4], smx[4];
    __shared__ float sbound;
    __shared__ int lcnt, gbase;
    const int tid = threadIdx.x;

    int tile_id = blockIdx.x;
    int idx  = tile_id / TPI;
    int trem = tile_id % TPI;
    int tyi = trem / TILES_X, txi = trem % TILES_X;
    int gy = tyi*14, gx = txi*28;      // interior origin
    int cc = idx >> 2, bb = idx & 3;
    const float* w = in + (size_t)(bb*3 + cc) * GN;
    int rep = trem & 31;               // minmax replica
    int seg = trem & 15;               // list segment

    // bound = 0.05 * sum(image) from 49 partials (fixed-order -> identical per image)
    if (tid < 64) {
        float p = (tid < 49) ? ws[WS_SUMP + idx*49 + tid] : 0.f;
        #pragma unroll
        for (int off = 32; off; off >>= 1) p += __shfl_down(p, off);
        if (tid == 0) { sbound = 0.05f * p; lcnt = 0; }
    }

    // stage border-clamped w halo tile 26 x 40
    int wy0 = gy - 6, wx0 = gx - 6;
    if (txi != 0 && txi != TILES_X-1) {
        // x-interior: rows contiguous in global (only y clamps); float2, aligned
        for (int i = tid; i < SH*20; i += 256) {
            int r = i / 20, q = i % 20;
            int yy = wy0 + r; yy = yy < 0 ? 0 : (yy > GH-1 ? GH-1 : yy);
            ((float2*)wt)[r*20 + q] = ((const float2*)(w + yy*GW + wx0))[q];
        }
    } else {
        for (int i = tid; i < WTN; i += 256) {
            int r = i / WTW, q = i % WTW;
            int yy = wy0 + r; yy = yy < 0 ? 0 : (yy > GH-1 ? GH-1 : yy);
            int xx = wx0 + q; xx = xx < 0 ? 0 : (xx > GW-1 ? GW-1 : xx);
            wt[i] = w[yy*GW + xx];
        }
    }
    __syncthreads();

    // horizontal pass: S1 = box sum, S2 = dx^2-weighted sum, per (w-row, F-col)
    for (int e = tid; e < SH*SW; e += 256) {
        int r = e / SW, fc = e % SW;
        int pxc = gx - 1 + fc; pxc = pxc < 0 ? 0 : (pxc > GW-1 ? GW-1 : pxc);
        const float* bp = wt + r*WTW + (pxc - wx0 - 5);
        float s1 = 0.f, s2 = 0.f;
        #pragma unroll
        for (int k = 0; k < 11; k++) {
            float v = bp[k];
            s1 += v;
            s2 = fmaf(KD2[k], v, s2);
        }
        S1[e] = s1; S2[e] = s2;
    }
    __syncthreads();

    // vertical pass: two F-points per thread (rows fy0, fy0+8), col fc
    const bool act = tid < 240;        // 8 row-starts x 30 cols
    int fy0 = act ? tid / 30 : 0;
    int fc  = act ? tid % 30 : 0;
    float bound = sbound;
    float fv[2] = {0.f, 0.f};
    if (act) {
        int pxc = gx - 1 + fc; pxc = pxc < 0 ? 0 : (pxc > GW-1 ? GW-1 : pxc);
        int cb = pxc - wx0 - 5;
        #pragma unroll
        for (int h = 0; h < 2; h++) {
            int fy = fy0 + h*8;
            int py = gy - 1 + fy; int pyc = py < 0 ? 0 : (py > GH-1 ? GH-1 : py);
            int vb = pyc - wy0 - 5;
            float a = 0.f, b2 = 0.f, cumT = 0.f;
            #pragma unroll
            for (int k = 0; k < 11; k++) {
                float s1 = S1[(vb+k)*SW + fc];
                float s2 = S2[(vb+k)*SW + fc];
                a = fmaf(KD2[k], s1, a);
                b2 += s2;
                cumT += s1;
            }
            float acc = a + b2;
            if (bound < cumT) {        // exact grouped path (never for bench input)
                const float* basep = wt + vb*WTW + cb;
                float cum = 0.f; acc = 0.f;
                for (int g = 0; g < NG; g++) {
                    float gs = 0.f;
                    for (int r = 0; r < 11; r++)
                        for (int c = 0; c < 11; c++)
                            if (TG.g[r][c] == g) gs += basep[r*WTW + c];
                    float v = bound - cum;
                    v = v < 0.f ? 0.f : v;
                    v = v > gs ? gs : v;
                    acc = fmaf(v, TG.gd2[g], acc);
                    cum += gs;
                }
            }
            fv[h] = sqrtf(acc / bound + 1e-12f);
            Ft[fy*32 + fc] = fv[h];
        }
    }
    float mnv = INFINITY, mxv = -INFINITY;
    if (act) { mnv = fminf(fv[0], fv[1]); mxv = fmaxf(fv[0], fv[1]); }  // halo = clamped dups, safe
    #pragma unroll
    for (int off = 32; off; off >>= 1) {
        mnv = fminf(mnv, __shfl_down(mnv, off));
        mxv = fmaxf(mxv, __shfl_down(mxv, off));
    }
    if ((tid & 63) == 0) { smn[tid>>6] = mnv; smx[tid>>6] = mxv; }
    __syncthreads();                   // Ft complete + smn/smx ready
    if (tid == 0) {
        float bm = fminf(fminf(smn[0], smn[1]), fminf(smn[2], smn[3]));
        float bX = fmaxf(fmaxf(smx[0], smx[1]), fmaxf(smx[2], smx[3]));
        atomicMax((unsigned int*)&ws[WS_MM + (idx*32 + rep)*2],     ~__float_as_uint(bm));
        atomicMax((unsigned int*)&ws[WS_MM + (idx*32 + rep)*2 + 1],  __float_as_uint(bX));
    }

    // 3x3 is_min / death on 28x14 interior (F rows 1..14, cols 1..28)
    if (act && fc >= 1 && fc <= 28) {
        #pragma unroll
        for (int h = 0; h < 2; h++) {
            int fy = fy0 + h*8;
            if (fy >= 1 && fy <= 14) {
                const float* Fc = Ft + (fy-1)*32 + (fc-1);
                float f = fv[h];
                float mn = f, mx = f;
                #pragma unroll
                for (int dy = 0; dy < 3; dy++)
                    #pragma unroll
                    for (int dx = 0; dx < 3; dx++) {
                        float v = Fc[dy*32 + dx];
                        mn = fminf(mn, v); mx = fmaxf(mx, v);
                    }
                if (f <= mn) {
                    int s = atomicAdd(&lcnt, 1);
                    sb[s] = f; sd[s] = mx;
                }
            }
        }
    }
    __syncthreads();
    if (tid == 0)                      // 8 blocks per (image,segment) counter
        gbase = atomicAdd((int*)ws + WS_CTR + idx*SEGN + seg, lcnt);
    __syncthreads();
    int n = lcnt, gb = gbase;
    float2* list = (float2*)(ws + WS_LIST) + (size_t)idx * CAP + seg * SEGCAP;
    for (int i = tid; i < n; i += 256)
        if (gb + i < SEGCAP) list[gb + i] = make_float2(sb[i], sd[i]);
}

// Node 3: top-2 landscape per (image,t). NO fences/ticket (R12's 40us lesson:
// 300 blocks x 2 device-scope __threadfence = L2 writeback storm). Cross-kernel
// visibility of lam comes from the dispatch boundary.
__global__ __launch_bounds__(256) void k_top2(float* __restrict__ ws) {
    __shared__ float r0s[4], r1s[4];
    __shared__ float s_tm[2];
    const int tid = threadIdx.x;
    int jb = blockIdx.x;
    int idx = jb / NT, t = jb % NT;

    // reduce the 32 minmax replicas (one 32-lane shuffle tree)
    if (tid < 32) {
        unsigned mn = ((const unsigned*)ws)[WS_MM + (idx*32 + tid)*2];
        unsigned mx = ((const unsigned*)ws)[WS_MM + (idx*32 + tid)*2 + 1];
        #pragma unroll
        for (int off = 16; off; off >>= 1) {
            unsigned m2 = __shfl_down(mn, off);
            unsigned x2 = __shfl_down(mx, off);
            mn = mn > m2 ? mn : m2;
            mx = mx > x2 ? mx : x2;
        }
        if (tid == 0) { s_tm[0] = __uint_as_float(~mn); s_tm[1] = __uint_as_float(mx); }
    }
    __syncthreads();
    float tmin = s_tm[0], tmax = s_tm[1];
    float tss = tmin + (tmax - tmin) * ((float)t / 24.0f);
    float a0 = 0.f, a1 = 0.f;
    for (int seg = 0; seg < SEGN; seg++) {
        int nm = ((const int*)ws)[WS_CTR + idx*SEGN + seg];
        nm = nm < SEGCAP ? nm : SEGCAP;
        const float2* list = (const float2*)(ws + WS_LIST) + (size_t)idx * CAP + seg * SEGCAP;
        for (int i = tid; i < nm; i += 256) {
            float2 p = list[i];
            float v = fmaxf(fminf(tss - p.x, p.y - tss), 0.f);
            float n0 = fmaxf(a0, v);
            a1 = fmaxf(a1, fminf(a0, v));
            a0 = n0;
        }
    }
    #pragma unroll
    for (int off = 32; off; off >>= 1) {
        float b0 = __shfl_down(a0, off);
        float b1 = __shfl_down(a1, off);
        float n0 = fmaxf(a0, b0);
        a1 = fmaxf(fminf(a0, b0), fmaxf(a1, b1));
        a0 = n0;
    }
    if ((tid & 63) == 0) { r0s[tid>>6] = a0; r1s[tid>>6] = a1; }
    __syncthreads();
    if (tid == 0) {
        float c0 = r0s[0], c1 = r1s[0];
        #pragma unroll
        for (int wv = 1; wv < 4; wv++) {
            float b0 = r0s[wv], b1 = r1s[wv];
            float n0 = fmaxf(c0, b0);
            c1 = fmaxf(fminf(c0, b0), fmaxf(c1, b1));
            c0 = n0;
        }
        ws[WS_LAM + (size_t)idx*50 + t*2    ] = c0;
        ws[WS_LAM + (size_t)idx*50 + t*2 + 1] = c1;
    }
}

// Node 4: linear heads + signal (single block; plain loads, dispatch-boundary sync).
__global__ __launch_bounds__(256) void k_head(
        const float* __restrict__ W1, const float* __restrict__ b1,
        const float* __restrict__ W2, const float* __restrict__ b2,
        const float* __restrict__ W3, const float* __restrict__ b3,
        const float* __restrict__ fcw, const float* __restrict__ fcb,
        const float* __restrict__ ws, float* __restrict__ out)
{
    __shared__ float lamS[600];
    __shared__ float xsh[600];
    const int tid = threadIdx.x;
    for (int i = tid; i < 600; i += 256) lamS[i] = ws[WS_LAM + i];
    __syncthreads();
    for (int j = tid; j < 600; j += 256) {
        int b = j / 150, r = j % 150, c = r / 50, o = r % 50;
        const float* Wc = (c == 0) ? W1 : (c == 1) ? W2 : W3;
        const float* bc = (c == 0) ? b1 : (c == 1) ? b2 : b3;
        const float* lam = lamS + (c*4 + b) * 50;
        float acc = bc[o];
        for (int f2 = 0; f2 < 50; f2++) acc += lam[f2] * Wc[o*50 + f2];
        xsh[j] = acc;
    }
    __syncthreads();
    if (tid < 150) {                     // signal = sum_b |x|
        float s = 0.f;
        for (int b = 0; b < 4; b++) s += fabsf(xsh[b*150 + tid]);
        out[28 + tid] = s;
    }
    if (tid < 28) {                      // output = relu(x) @ fc_w.T + fc_b
        int b = tid / 7, o = tid % 7;
        float acc = fcb[o];
        for (int j = 0; j < 150; j++) acc += fmaxf(xsh[b*150 + j], 0.f) * fcw[o*150 + j];
        out[b*7 + o] = acc;
    }
}

extern "C" void kernel_launch(void* const* d_in, const int* in_sizes, int n_in,
                              void* d_out, int out_size, void* d_ws, size_t ws_size,
                              hipStream_t stream) {
    const float* in  = (const float*)d_in[0];
    const float* W1  = (const float*)d_in[1];
    const float* b1  = (const float*)d_in[2];
    const float* W2  = (const float*)d_in[3];
    const float* b2  = (const float*)d_in[4];
    const float* W3  = (const float*)d_in[5];
    const float* b3  = (const float*)d_in[6];
    const float* fcw = (const float*)d_in[7];
    const float* fcb = (const float*)d_in[8];
    float* ws  = (float*)d_ws;
    float* out = (float*)d_out;

    k_sums<<<NSUMJ,  256, 0, stream>>>(in, ws);
    k_dtm <<<NTILES, 256, 0, stream>>>(in, ws);
    k_top2<<<300,    256, 0, stream>>>(ws);
    k_head<<<1,      256, 0, stream>>>(W1, b1, W2, b2, W3, b3, fcw, fcb, ws, out);
}